// Round 7
// baseline (1164.095 us; speedup 1.0000x reference)
//
#include <hip/hip_runtime.h>
#include <math.h>

#define Tlen 20
#define Vv 10000
#define BT 20480
#define SCAN_BLOCKS 512

typedef __attribute__((ext_vector_type(8))) short b16x8;
typedef __attribute__((ext_vector_type(4))) float f32x4;

__device__ __forceinline__ unsigned short f2b(float f){
    union { float f; unsigned u; } v; v.f = f;
    unsigned r = v.u + 0x7FFFu + ((v.u >> 16) & 1u);
    return (unsigned short)(r >> 16);
}
__device__ __forceinline__ float b2f(unsigned short h){
    union { unsigned u; float f; } v; v.u = ((unsigned)h) << 16;
    return v.f;
}
__device__ __forceinline__ void gload16(const void* g, void* l){
    __builtin_amdgcn_global_load_lds(
        (const __attribute__((address_space(1))) unsigned int*)g,
        (__attribute__((address_space(3))) unsigned int*)l, 16, 0, 0);
}
__device__ __forceinline__ float fast_sig(float x){ return 1.f / (1.f + __expf(-x)); }
__device__ __forceinline__ float fast_tanh(float x){ return 1.f - 2.f / (__expf(2.f * x) + 1.f); }

// ---------------- bf16 MFMA GEMM 64x64 tile (encoder/heads) ----------------
template<int ACT, int OUTF, int OUTB, int AF32>
__global__ __launch_bounds__(256) void gemm_bf_k(
        const void* __restrict__ Av, const unsigned short* __restrict__ BTp,
        const float* __restrict__ bias, float* __restrict__ Cf,
        unsigned short* __restrict__ Cb, int M, int N, int K)
{
    __shared__ __align__(16) char As[64 * 80];
    __shared__ __align__(16) char Bs[64 * 80];
    const int tid = threadIdx.x;
    const int wid = tid >> 6, lane = tid & 63;
    const int row0 = blockIdx.y * 64, col0 = blockIdx.x * 64;
    const int srow = tid >> 2, sslot = tid & 3;
    f32x4 acc[4];
    #pragma unroll
    for (int i = 0; i < 4; i++) acc[i] = (f32x4){0.f, 0.f, 0.f, 0.f};
    const int afoff = (wid * 16 + (lane & 15)) * 80 + (lane >> 4) * 16;
    for (int k0 = 0; k0 < K; k0 += 32) {
        b16x8 av, bv;
        if (AF32) {
            const float* Af = (const float*)Av + (size_t)(row0 + srow) * K + k0 + sslot * 8;
            float4 a0 = *(const float4*)Af;
            float4 a1 = *(const float4*)(Af + 4);
            av[0]=(short)f2b(a0.x); av[1]=(short)f2b(a0.y); av[2]=(short)f2b(a0.z); av[3]=(short)f2b(a0.w);
            av[4]=(short)f2b(a1.x); av[5]=(short)f2b(a1.y); av[6]=(short)f2b(a1.z); av[7]=(short)f2b(a1.w);
        } else {
            av = *(const b16x8*)((const unsigned short*)Av + (size_t)(row0 + srow) * K + k0 + sslot * 8);
        }
        bv = *(const b16x8*)(BTp + (size_t)(col0 + srow) * K + k0 + sslot * 8);
        __syncthreads();
        *(b16x8*)(As + srow * 80 + sslot * 16) = av;
        *(b16x8*)(Bs + srow * 80 + sslot * 16) = bv;
        __syncthreads();
        b16x8 af = *(const b16x8*)(As + afoff);
        #pragma unroll
        for (int ct = 0; ct < 4; ct++) {
            b16x8 bf = *(const b16x8*)(Bs + (ct * 16 + (lane & 15)) * 80 + (lane >> 4) * 16);
            acc[ct] = __builtin_amdgcn_mfma_f32_16x16x32_bf16(af, bf, acc[ct], 0, 0, 0);
        }
    }
    const int orow = row0 + wid * 16 + (lane >> 4) * 4;
    #pragma unroll
    for (int ct = 0; ct < 4; ct++) {
        int col = col0 + ct * 16 + (lane & 15);
        float bb = bias ? bias[col] : 0.f;
        #pragma unroll
        for (int r = 0; r < 4; r++) {
            float v = acc[ct][r] + bb;
            if (ACT == 1) v = 0.5f * v * (1.f + erff(v * 0.70710678118654752f));
            else if (ACT == 2) v = tanhf(v);
            size_t idx = (size_t)(orow + r) * N + col;
            if (OUTF) Cf[idx] = v;
            if (OUTB) Cb[idx] = f2b(v);
        }
    }
}

// ---------------- big MFMA GEMM: 128x128 tile, gload_lds, dbuf, swizzled ----------------
__global__ __launch_bounds__(256) void gemm_big_k(
        const unsigned short* __restrict__ Aptr, const unsigned short* __restrict__ Bptr,
        unsigned short* __restrict__ C, int N, int K)
{
    __shared__ __align__(16) unsigned short As[2][128 * 32];
    __shared__ __align__(16) unsigned short Bs[2][128 * 32];
    const int tid = threadIdx.x, w = tid >> 6, lane = tid & 63;
    const int l15 = lane & 15, lh = lane >> 4;
    const int nwg = gridDim.x * gridDim.y;
    const int orig = blockIdx.y * gridDim.x + blockIdx.x;
    const int q = nwg >> 3, r = nwg & 7;
    const int xcd = orig & 7, pos = orig >> 3;
    const int wgid = (xcd < r ? xcd * (q + 1) : r * (q + 1) + (xcd - r) * q) + pos;
    const int bx = wgid % gridDim.x, by = wgid / gridDim.x;
    const int row0 = by * 128, col0 = bx * 128;
    const int wr = w >> 1, wc = w & 1;
    const int slw = ((lane & 3) ^ ((lane >> 2) & 3) ^ ((lane >> 4) & 3)) & 3;
    const int pa  = (lh ^ (l15 & 3) ^ ((l15 >> 2) & 3)) & 3;
    f32x4 acc[4][4];
    #pragma unroll
    for (int i = 0; i < 4; i++)
        #pragma unroll
        for (int j = 0; j < 4; j++) acc[i][j] = (f32x4){0.f, 0.f, 0.f, 0.f};
    const int nkt = K >> 5;
    #pragma unroll
    for (int c = 0; c < 2; c++) {
        int ch = w * 2 + c, rr = ch * 16 + (lane >> 2);
        gload16(Aptr + (size_t)(row0 + rr) * K + slw * 8, &As[0][ch * 512]);
        gload16(Bptr + (size_t)(col0 + rr) * K + slw * 8, &Bs[0][ch * 512]);
    }
    __syncthreads();
    for (int kt = 0; kt < nkt; kt++) {
        const int buf = kt & 1;
        if (kt + 1 < nkt) {
            const int k0 = (kt + 1) << 5;
            #pragma unroll
            for (int c = 0; c < 2; c++) {
                int ch = w * 2 + c, rr = ch * 16 + (lane >> 2);
                gload16(Aptr + (size_t)(row0 + rr) * K + k0 + slw * 8, &As[buf ^ 1][ch * 512]);
                gload16(Bptr + (size_t)(col0 + rr) * K + k0 + slw * 8, &Bs[buf ^ 1][ch * 512]);
            }
        }
        b16x8 af[4], bf[4];
        #pragma unroll
        for (int f = 0; f < 4; f++) {
            af[f] = *(const b16x8*)(&As[buf][(wr * 64 + f * 16 + l15) * 32 + pa * 8]);
            bf[f] = *(const b16x8*)(&Bs[buf][(wc * 64 + f * 16 + l15) * 32 + pa * 8]);
        }
        #pragma unroll
        for (int i = 0; i < 4; i++)
            #pragma unroll
            for (int j = 0; j < 4; j++)
                acc[i][j] = __builtin_amdgcn_mfma_f32_16x16x32_bf16(af[i], bf[j], acc[i][j], 0, 0, 0);
        __syncthreads();
    }
    #pragma unroll
    for (int i = 0; i < 4; i++) {
        const int orow = row0 + wr * 64 + i * 16 + lh * 4;
        #pragma unroll
        for (int j = 0; j < 4; j++) {
            const int col = col0 + wc * 64 + j * 16 + l15;
            #pragma unroll
            for (int rr = 0; rr < 4; rr++)
                C[(size_t)(orow + rr) * N + col] = f2b(acc[i][j][rr]);
        }
    }
}

// ---------------- merged weight-prep ----------------
__device__ void tileT_dev(const float* __restrict__ W, unsigned short* __restrict__ WT,
        int K, int N, int bx, int by)
{
    __shared__ float s[32][33];
    const int n0 = bx * 32, k0 = by * 32;
    const int tx = threadIdx.x & 31, ty = threadIdx.x >> 5;
    #pragma unroll
    for (int i = 0; i < 32; i += 8) {
        int k = k0 + ty + i, n = n0 + tx;
        s[ty + i][tx] = (k < K && n < N) ? W[(size_t)k * N + n] : 0.f;
    }
    __syncthreads();
    #pragma unroll
    for (int i = 0; i < 32; i += 8) {
        int n = n0 + ty + i, k = k0 + tx;
        if (n < N && k < K) WT[(size_t)n * K + k] = f2b(s[tx][ty + i]);
    }
}

__global__ __launch_bounds__(256) void prep_all_k(
        const float* __restrict__ Wih, const float* __restrict__ Whh,
        const float* __restrict__ frW, const float* __restrict__ b1W1,
        const float* __restrict__ b1W2, const float* __restrict__ b2W1,
        const float* __restrict__ b2W2, const float* __restrict__ encW,
        const float* __restrict__ aW1, const float* __restrict__ cW1,
        const float* __restrict__ aW3, const float* __restrict__ aW2,
        const float* __restrict__ cW2, const float* __restrict__ ab1,
        const float* __restrict__ cb1, const float* __restrict__ ab2,
        const float* __restrict__ cb2, const float* __restrict__ emb,
        const float* __restrict__ img, const float* __restrict__ box,
        unsigned short* __restrict__ WihT, unsigned short* __restrict__ WhhT,
        unsigned short* __restrict__ frWT, unsigned short* __restrict__ b1W1T,
        unsigned short* __restrict__ b1W2T, unsigned short* __restrict__ b2W1T,
        unsigned short* __restrict__ b2W2T, unsigned short* __restrict__ encWT,
        unsigned short* __restrict__ W1cT, unsigned short* __restrict__ W2cT,
        unsigned short* __restrict__ WT3, float* __restrict__ b1c,
        float* __restrict__ b2c, unsigned short* __restrict__ embB,
        unsigned short* __restrict__ A0, unsigned* __restrict__ barflags)
{
    int bid = blockIdx.x;
    const int tid = threadIdx.x;
    if (bid < 768) { tileT_dev(Wih, WihT, 512, 1536, bid % 48, bid / 48); return; }
    bid -= 768;
    if (bid < 768) { tileT_dev(Whh, WhhT, 512, 1536, bid % 48, bid / 48); return; }
    bid -= 768;
    if (bid < 1152) { tileT_dev(frW, frWT, 2304, 512, bid % 16, bid / 16); return; }
    bid -= 1152;
    if (bid < 256) { tileT_dev(b1W1, b1W1T, 512, 512, bid % 16, bid / 16); return; }
    bid -= 256;
    if (bid < 256) { tileT_dev(b1W2, b1W2T, 512, 512, bid % 16, bid / 16); return; }
    bid -= 256;
    if (bid < 256) { tileT_dev(b2W1, b2W1T, 512, 512, bid % 16, bid / 16); return; }
    bid -= 256;
    if (bid < 256) { tileT_dev(b2W2, b2W2T, 512, 512, bid % 16, bid / 16); return; }
    bid -= 256;
    if (bid < 256) { tileT_dev(encW, encWT, 512, 512, bid % 16, bid / 16); return; }
    bid -= 256;
    if (bid < 32) { tileT_dev(aW1, W1cT, 512, 64, bid % 2, bid / 2); return; }
    bid -= 32;
    if (bid < 32) { tileT_dev(cW1, W1cT + (size_t)64 * 512, 512, 64, bid % 2, bid / 2); return; }
    bid -= 32;
    if (bid < 626) { tileT_dev(aW3, WT3, 64, 10000, bid % 313, bid / 313); return; }
    bid -= 626;
    if (bid < 64) {
        int idx = bid * 256 + tid;
        int j = idx >> 7, k = idx & 127;
        float v = 0.f;
        if (j < 64 && k < 64) v = aW2[(size_t)k * 64 + j];
        else if (j >= 64 && k >= 64) v = cW2[(size_t)(k - 64) * 64 + (j - 64)];
        W2cT[idx] = f2b(v);
        return;
    }
    bid -= 64;
    if (bid < 1) {
        if (tid == 0) { barflags[0] = 0u; barflags[1] = 0u; }
        if (tid < 128) b1c[tid] = (tid < 64) ? ab1[tid] : cb1[tid - 64];
        else { int i = tid - 128; b2c[i] = (i < 64) ? ab2[i] : cb2[i - 64]; }
        return;
    }
    bid -= 1;
    if (bid < 5056) {
        int idx = bid * 256 + tid;
        int row = idx >> 7, c4 = (idx & 127) * 4;
        float4 v = {0.f, 0.f, 0.f, 0.f};
        if (row < Vv) v = *(const float4*)(emb + (size_t)row * 512 + c4);
        ushort4 o; o.x = f2b(v.x); o.y = f2b(v.y); o.z = f2b(v.z); o.w = f2b(v.w);
        *(ushort4*)(embB + (size_t)row * 512 + c4) = o;
        return;
    }
    bid -= 5056;
    {
        int idx = bid * 256 + tid;
        int row = idx / 576, c4 = (idx - row * 576) * 4;
        float4 v = (c4 < 2048) ? *(const float4*)(img + (size_t)row * 2048 + c4)
                               : *(const float4*)(box + (size_t)row * 256 + (c4 - 2048));
        ushort4 o; o.x = f2b(v.x); o.y = f2b(v.y); o.z = f2b(v.z); o.w = f2b(v.w);
        *(ushort4*)(A0 + (size_t)row * 2304 + c4) = o;
    }
}

// ---------------- LayerNorm over D=512 ----------------
__global__ __launch_bounds__(256) void ln_k(const float* __restrict__ Xa,
        const float* __restrict__ Xb, const float* __restrict__ g,
        const float* __restrict__ be, float* __restrict__ Y)
{
    const int row = blockIdx.x, tid = threadIdx.x;
    const size_t base = (size_t)row * 512;
    float a0 = Xa[base + tid], a1 = Xa[base + tid + 256];
    if (Xb) { a0 += Xb[base + tid]; a1 += Xb[base + tid + 256]; }
    float s = a0 + a1;
    #pragma unroll
    for (int o = 32; o; o >>= 1) s += __shfl_xor(s, o, 64);
    __shared__ float red[8];
    const int lane = tid & 63, wid = tid >> 6;
    if (!lane) red[wid] = s;
    __syncthreads();
    const float mean = (red[0] + red[1] + red[2] + red[3]) * (1.f / 512.f);
    const float d0 = a0 - mean, d1 = a1 - mean;
    float q = d0 * d0 + d1 * d1;
    #pragma unroll
    for (int o = 32; o; o >>= 1) q += __shfl_xor(q, o, 64);
    if (!lane) red[4 + wid] = q;
    __syncthreads();
    const float var = (red[4] + red[5] + red[6] + red[7]) * (1.f / 512.f);
    const float inv = rsqrtf(var + 1e-5f);
    float y0 = d0 * inv, y1 = d1 * inv;
    if (g) { y0 = y0 * g[tid] + be[tid]; y1 = y1 * g[tid + 256] + be[tid + 256]; }
    Y[base + tid] = y0; Y[base + tid + 256] = y1;
}

// ---------------- persistent GRU scan with software grid barrier ----------------
// 512 blocks, guaranteed co-resident: LDS 48KB (3/CU cap), launch_bounds(256,2)
// (>=2 blocks/CU) -> 2*256 = 512. Wih slice staged ONCE; 19 internal barriers.
__global__ __launch_bounds__(256, 2) void gru_scan_bar_k(
        const unsigned short* __restrict__ H0,     // [1024][512] bf16
        const unsigned short* __restrict__ WihT,   // [1536][512] bf16
        const float* __restrict__ bih, const float* __restrict__ bhh,
        const unsigned short* __restrict__ GHemb,  // [10112][1536] bf16 (no bias)
        const float* __restrict__ emb, const int* __restrict__ acts,
        unsigned short* __restrict__ HALLb,        // [20][1024][512] bf16
        unsigned* __restrict__ bar)                // bar[0]=cnt, bar[1]=gen (zeroed by prep)
{
    __shared__ __align__(16) unsigned short sB[48 * 512];   // 49152 B
    const int tid = threadIdx.x, w = tid >> 6, lane = tid & 63;
    const int l15 = lane & 15, lh = lane >> 4;
    const int d0 = blockIdx.x * 16;
    const int rows0 = blockIdx.y * 64 + w * 16;
    // stage Wih slice once: 48 rows x 1KB, source pre-swizzled by row&7
    #pragma unroll
    for (int c = 0; c < 12; c++) {
        const int ch = w * 12 + c;
        const int g = ch >> 4, col = ch & 15;
        const int sl = lane ^ (ch & 7);
        gload16(WihT + (size_t)(g * 512 + d0 + col) * 512 + sl * 8, &sB[ch * 512]);
    }
    const int d = d0 + l15;
    const float bi0 = bih[d], bi1 = bih[512 + d], bi2 = bih[1024 + d];
    const float bh0 = bhh[d], bh1 = bhh[512 + d], bh2 = bhh[1024 + d];
    __syncthreads();
    const unsigned short* Hprev = H0;
    for (int t = 0; t < Tlen; ++t) {
        if (t) {   // grid barrier: step t-1 writes -> visible to step t reads
            __syncthreads();
            if (tid == 0) {
                unsigned g = __hip_atomic_load(&bar[1], __ATOMIC_RELAXED, __HIP_MEMORY_SCOPE_AGENT);
                unsigned a = __hip_atomic_fetch_add(&bar[0], 1u, __ATOMIC_ACQ_REL, __HIP_MEMORY_SCOPE_AGENT);
                if (a + 1u == (unsigned)SCAN_BLOCKS) {
                    __hip_atomic_store(&bar[0], 0u, __ATOMIC_RELAXED, __HIP_MEMORY_SCOPE_AGENT);
                    __hip_atomic_store(&bar[1], g + 1u, __ATOMIC_RELEASE, __HIP_MEMORY_SCOPE_AGENT);
                } else {
                    while (__hip_atomic_load(&bar[1], __ATOMIC_ACQUIRE, __HIP_MEMORY_SCOPE_AGENT) == g)
                        __builtin_amdgcn_s_sleep(1);
                }
            }
            __syncthreads();
        }
        const unsigned short* Arow = Hprev + (size_t)(rows0 + l15) * 512 + lh * 8;
        b16x8 a[16];
        #pragma unroll
        for (int kk = 0; kk < 16; kk++) a[kk] = *(const b16x8*)(Arow + kk * 32);
        f32x4 ar = (f32x4){0.f,0.f,0.f,0.f}, az = ar, an = ar;
        #pragma unroll
        for (int kk = 0; kk < 16; kk++) {
            const int sl = ((kk * 4 + lh) ^ (l15 & 7));
            b16x8 b0 = *(const b16x8*)(&sB[(l15) * 512 + sl * 8]);
            b16x8 b1 = *(const b16x8*)(&sB[(16 + l15) * 512 + sl * 8]);
            b16x8 b2 = *(const b16x8*)(&sB[(32 + l15) * 512 + sl * 8]);
            ar = __builtin_amdgcn_mfma_f32_16x16x32_bf16(a[kk], b0, ar, 0, 0, 0);
            az = __builtin_amdgcn_mfma_f32_16x16x32_bf16(a[kk], b1, az, 0, 0, 0);
            an = __builtin_amdgcn_mfma_f32_16x16x32_bf16(a[kk], b2, an, 0, 0, 0);
        }
        unsigned short* Hout = HALLb + (size_t)t * 524288;
        #pragma unroll
        for (int reg = 0; reg < 4; reg++) {
            const int row = rows0 + lh * 4 + reg;
            float hr = bh0, hz = bh1, hn = bh2, ix = 0.f;
            if (t) {
                const int ap = acts[row * Tlen + t - 1];
                const size_t gb = (size_t)ap * 1536;
                hr += b2f(GHemb[gb + d]);
                hz += b2f(GHemb[gb + 512 + d]);
                hn += b2f(GHemb[gb + 1024 + d]);
                ix = emb[(size_t)ap * 512 + d];
            }
            const float rr = fast_sig(ar[reg] + bi0 + hr);
            const float zz = fast_sig(az[reg] + bi1 + hz);
            const float nn = fast_tanh(an[reg] + bi2 + rr * hn);
            Hout[(size_t)row * 512 + d] = f2b((1.f - zz) * nn + zz * ix);
        }
        Hprev = Hout;
    }
}

// ---------------- logits: V-split MFMA + partial exp-sums ----------------
__global__ __launch_bounds__(256) void logits3_k(const unsigned short* __restrict__ A2b,
        const unsigned short* __restrict__ WT3, const float* __restrict__ b3,
        const float* __restrict__ wmask, float* __restrict__ Spart,
        float* __restrict__ Wmpart)
{
    __shared__ __align__(16) char Bs[64 * 144];
    __shared__ float bmS[64];
    const int tid = threadIdx.x, wid = tid >> 6, lane = tid & 63;
    const int r0 = blockIdx.x * 64;
    const int c0 = blockIdx.y * 640;
    const int cend = (c0 + 640 < 5056) ? c0 + 640 : 5056;
    const size_t abase = (size_t)(r0 + wid * 16 + (lane & 15)) * 128 + (lane >> 4) * 8;
    const b16x8 af0 = *(const b16x8*)(A2b + abase);
    const b16x8 af1 = *(const b16x8*)(A2b + abase + 32);
    float S[4] = {0.f, 0.f, 0.f, 0.f}, Wm[4] = {0.f, 0.f, 0.f, 0.f};
    for (int cc = c0; cc < cend; cc += 64) {
        __syncthreads();
        #pragma unroll
        for (int i = 0; i < 2; i++) {
            int e = tid + i * 256;
            int rr = e >> 3, slot = e & 7;
            b16x8 wv = *(const b16x8*)(WT3 + (size_t)(cc + rr) * 64 + slot * 8);
            *(b16x8*)(Bs + rr * 144 + slot * 16) = wv;
        }
        if (tid < 64) bmS[tid] = b3[cc + tid] + wmask[cc + tid];
        __syncthreads();
        #pragma unroll
        for (int ct = 0; ct < 4; ct++) {
            const int colb = (ct * 16 + (lane & 15)) * 144 + (lane >> 4) * 16;
            b16x8 bf0 = *(const b16x8*)(Bs + colb);
            b16x8 bf1 = *(const b16x8*)(Bs + colb + 64);
            f32x4 acc = (f32x4){0.f, 0.f, 0.f, 0.f};
            acc = __builtin_amdgcn_mfma_f32_16x16x32_bf16(af0, bf0, acc, 0, 0, 0);
            acc = __builtin_amdgcn_mfma_f32_16x16x32_bf16(af1, bf1, acc, 0, 0, 0);
            const float bm = bmS[ct * 16 + (lane & 15)];
            #pragma unroll
            for (int r = 0; r < 4; r++) {
                float l = acc[r] + bm;
                float e = __expf(l);
                S[r] += e;
                Wm[r] = fmaf(e, l, Wm[r]);
            }
        }
    }
    #pragma unroll
    for (int r = 0; r < 4; r++) {
        float s = S[r], w = Wm[r];
        #pragma unroll
        for (int o = 1; o < 16; o <<= 1) {
            s += __shfl_xor(s, o, 64);
            w += __shfl_xor(w, o, 64);
        }
        if ((lane & 15) == 0) {
            int row = r0 + wid * 16 + (lane >> 4) * 4 + r;
            Spart[blockIdx.y * BT + row] = s;
            Wmpart[blockIdx.y * BT + row] = w;
        }
    }
}

// ---------------- merged tail: entropy / logp / value / actions ----------------
__global__ __launch_bounds__(256) void tail_k(const float* __restrict__ Spart,
        const float* __restrict__ Wmpart, const unsigned short* __restrict__ L2b,
        const unsigned short* __restrict__ WT3, const float* __restrict__ b3,
        const float* __restrict__ wmask, const int* __restrict__ acts,
        const float* __restrict__ cw3, const float* __restrict__ cb3,
        float* __restrict__ out)
{
    const int bid = blockIdx.x, tid = threadIdx.x;
    if (bid < 80) {
        const int rt = bid * 256 + tid;
        float s = 0.f, wm = 0.f;
        #pragma unroll
        for (int j = 0; j < 8; j++) { s += Spart[j * BT + rt]; wm += Wmpart[j * BT + rt]; }
        const float l = logf(s);
        const int t = rt >> 10, b = rt & 1023;
        out[2 * BT + b * Tlen + t] = l - wm / s;
    } else if (bid < 160) {
        const int rt = (bid - 80) * 256 + tid;
        float s = 0.f;
        #pragma unroll
        for (int j = 0; j < 8; j++) s += Spart[j * BT + rt];
        const int t = rt >> 10, b = rt & 1023;
        const int a = acts[b * Tlen + t];
        const unsigned short* ar = L2b + (size_t)rt * 128;
        const unsigned short* wr = WT3 + (size_t)a * 64;
        float dot = 0.f;
        #pragma unroll 16
        for (int k = 0; k < 64; k++) dot = fmaf(b2f(ar[k]), b2f(wr[k]), dot);
        out[BT + b * Tlen + t] = dot + b3[a] + wmask[a] - logf(s);
    } else if (bid < 240) {
        const int rt = (bid - 160) * 256 + tid;
        const unsigned short* c = L2b + (size_t)rt * 128 + 64;
        float s = cb3[0];
        #pragma unroll 16
        for (int k = 0; k < 64; k++) s = fmaf(b2f(c[k]), cw3[k], s);
        const int t = rt >> 10, b = rt & 1023;
        out[3 * BT + b * Tlen + t] = s;
    } else {
        const int rt = (bid - 240) * 256 + tid;
        out[rt] = (float)acts[rt];
    }
}

extern "C" void kernel_launch(void* const* d_in, const int* in_sizes, int n_in,
                              void* d_out, int out_size, void* d_ws, size_t ws_size,
                              hipStream_t stream)
{
    const float* img  = (const float*)d_in[0];
    const float* box  = (const float*)d_in[1];
    const int*   acts = (const int*)d_in[2];
    const float* fr_W = (const float*)d_in[3];
    const float* fr_b = (const float*)d_in[4];
    const float* b1W1 = (const float*)d_in[5];
    const float* b1b1 = (const float*)d_in[6];
    const float* b1W2 = (const float*)d_in[7];
    const float* b1b2 = (const float*)d_in[8];
    const float* b2W1 = (const float*)d_in[9];
    const float* b2b1 = (const float*)d_in[10];
    const float* b2W2 = (const float*)d_in[11];
    const float* b2b2 = (const float*)d_in[12];
    const float* lng  = (const float*)d_in[13];
    const float* lnb  = (const float*)d_in[14];
    const float* encW = (const float*)d_in[15];
    const float* encb = (const float*)d_in[16];
    const float* emb  = (const float*)d_in[17];
    const float* Wih  = (const float*)d_in[18];
    const float* bih  = (const float*)d_in[19];
    const float* Whh  = (const float*)d_in[20];
    const float* bhh  = (const float*)d_in[21];
    const float* aW1  = (const float*)d_in[22];
    const float* ab1  = (const float*)d_in[23];
    const float* aW2  = (const float*)d_in[24];
    const float* ab2  = (const float*)d_in[25];
    const float* aW3  = (const float*)d_in[26];
    const float* ab3  = (const float*)d_in[27];
    const float* cW1  = (const float*)d_in[28];
    const float* cb1  = (const float*)d_in[29];
    const float* cW2  = (const float*)d_in[30];
    const float* cb2  = (const float*)d_in[31];
    const float* cW3  = (const float*)d_in[32];
    const float* cb3  = (const float*)d_in[33];
    const float* wmask= (const float*)d_in[34];
    float* out = (float*)d_out;

    // ---- workspace ----
    char* w = (char*)d_ws;
    unsigned short* WihT  = (unsigned short*)w; w += (size_t)786432 * 2;
    unsigned short* WhhT  = (unsigned short*)w; w += (size_t)786432 * 2;
    unsigned short* frWT  = (unsigned short*)w; w += (size_t)1179648 * 2;
    unsigned short* b1W1T = (unsigned short*)w; w += (size_t)262144 * 2;
    unsigned short* b1W2T = (unsigned short*)w; w += (size_t)262144 * 2;
    unsigned short* b2W1T = (unsigned short*)w; w += (size_t)262144 * 2;
    unsigned short* b2W2T = (unsigned short*)w; w += (size_t)262144 * 2;
    unsigned short* encWT = (unsigned short*)w; w += (size_t)262144 * 2;
    unsigned short* W1cT  = (unsigned short*)w; w += (size_t)65536 * 2;
    unsigned short* W2cT  = (unsigned short*)w; w += (size_t)16384 * 2;
    unsigned short* WT3   = (unsigned short*)w; w += (size_t)640000 * 2;
    float* b1c = (float*)w;                     w += 128 * 4;
    float* b2c = (float*)w;                     w += 128 * 4;
    unsigned* barflags = (unsigned*)w;          w += 64 * 4;
    unsigned short* embB  = (unsigned short*)w; w += (size_t)10112 * 512 * 2;
    unsigned short* GHemb = (unsigned short*)w; w += (size_t)10112 * 1536 * 2;
    unsigned short* HALLb = (unsigned short*)w; w += (size_t)10485760 * 2;
    unsigned short* L1b   = (unsigned short*)w; w += (size_t)2621440 * 2;
    unsigned short* L2b   = (unsigned short*)w; w += (size_t)2621440 * 2;
    unsigned short* HB0   = (unsigned short*)w; w += (size_t)524288 * 2;
    float* Spart = (float*)w;                   w += (size_t)8 * BT * 4;
    float* Wmpart= (float*)w;                   w += (size_t)8 * BT * 4;
    char* arena = w;                            w += (size_t)20971520;

    unsigned short* A0 = (unsigned short*)arena;
    float* Xe  = (float*)(arena + 4718592);
    float* Ye  = Xe + 524288;
    float* T1e = Ye + 524288;
    float* T2e = T1e + 524288;

    const dim3 blk(256);

    // ---- all weight prep (incl. barrier-flag zeroing) in one launch ----
    prep_all_k<<<12083, blk, 0, stream>>>(Wih, Whh, fr_W, b1W1, b1W2, b2W1, b2W2,
            encW, aW1, cW1, aW3, aW2, cW2, ab1, cb1, ab2, cb2, emb, img, box,
            WihT, WhhT, frWT, b1W1T, b1W2T, b2W1T, b2W2T, encWT, W1cT, W2cT,
            WT3, b1c, b2c, embB, A0, barflags);

    // ---- GHemb = embB @ Whh^T over vocab ----
    gemm_big_k<<<dim3(12, 79), blk, 0, stream>>>(embB, WhhT, GHemb, 1536, 512);

    // ---- encoder (bf16 MFMA, LN fp32) ----
    gemm_bf_k<0, 1, 0, 0><<<dim3(8, 16), blk, 0, stream>>>(A0, frWT, fr_b, Xe, nullptr, 1024, 512, 2304);
    ln_k<<<1024, blk, 0, stream>>>(Xe, nullptr, nullptr, nullptr, Ye);
    gemm_bf_k<1, 1, 0, 1><<<dim3(8, 16), blk, 0, stream>>>(Ye, b1W1T, b1b1, T1e, nullptr, 1024, 512, 512);
    gemm_bf_k<0, 1, 0, 1><<<dim3(8, 16), blk, 0, stream>>>(T1e, b1W2T, b1b2, T2e, nullptr, 1024, 512, 512);
    ln_k<<<1024, blk, 0, stream>>>(T2e, Xe, nullptr, nullptr, Ye);
    gemm_bf_k<1, 1, 0, 1><<<dim3(8, 16), blk, 0, stream>>>(Ye, b2W1T, b2b1, T1e, nullptr, 1024, 512, 512);
    gemm_bf_k<0, 1, 0, 1><<<dim3(8, 16), blk, 0, stream>>>(T1e, b2W2T, b2b2, T2e, nullptr, 1024, 512, 512);
    ln_k<<<1024, blk, 0, stream>>>(Xe, T2e, lng, lnb, Ye);
    gemm_bf_k<0, 0, 1, 1><<<dim3(8, 16), blk, 0, stream>>>(Ye, encWT, encb, nullptr, HB0, 1024, 512, 512);

    // ---- whole GRU scan: ONE kernel, 19 internal grid barriers ----
    gru_scan_bar_k<<<dim3(32, 16), blk, 0, stream>>>(HB0, WihT, bih, bhh,
            GHemb, emb, acts, HALLb, barflags);

    // ---- fused heads ----
    gemm_bf_k<2, 0, 1, 0><<<dim3(2, 320), blk, 0, stream>>>(HALLb, W1cT, b1c,
            nullptr, L1b, BT, 128, 512);
    gemm_bf_k<2, 0, 1, 0><<<dim3(2, 320), blk, 0, stream>>>(L1b, W2cT, b2c,
            nullptr, L2b, BT, 128, 128);
    logits3_k<<<dim3(320, 8), blk, 0, stream>>>(L2b, WT3, ab3, wmask, Spart, Wmpart);
    tail_k<<<320, blk, 0, stream>>>(Spart, Wmpart, L2b, WT3, ab3, wmask, acts,
            cW3, cb3, out);
}

// Round 8
// 432.619 us; speedup vs baseline: 2.6908x; 2.6908x over previous
//
#include <hip/hip_runtime.h>
#include <math.h>

#define Tlen 20
#define Vv 10000
#define BT 20480

typedef __attribute__((ext_vector_type(8))) short b16x8;
typedef __attribute__((ext_vector_type(4))) float f32x4;

__device__ __forceinline__ unsigned short f2b(float f){
    union { float f; unsigned u; } v; v.f = f;
    unsigned r = v.u + 0x7FFFu + ((v.u >> 16) & 1u);
    return (unsigned short)(r >> 16);
}
__device__ __forceinline__ float b2f(unsigned short h){
    union { unsigned u; float f; } v; v.u = ((unsigned)h) << 16;
    return v.f;
}
__device__ __forceinline__ void gload16(const void* g, void* l){
    __builtin_amdgcn_global_load_lds(
        (const __attribute__((address_space(1))) unsigned int*)g,
        (__attribute__((address_space(3))) unsigned int*)l, 16, 0, 0);
}
__device__ __forceinline__ float fast_sig(float x){ return 1.f / (1.f + __expf(-x)); }
__device__ __forceinline__ float fast_tanh(float x){ return 1.f - 2.f / (__expf(2.f * x) + 1.f); }

// ---------------- bf16 MFMA GEMM 64x64 tile (fr / enc / heads) ----------------
template<int ACT, int OUTF, int OUTB, int AF32>
__global__ __launch_bounds__(256) void gemm_bf_k(
        const void* __restrict__ Av, const unsigned short* __restrict__ BTp,
        const float* __restrict__ bias, float* __restrict__ Cf,
        unsigned short* __restrict__ Cb, int M, int N, int K)
{
    __shared__ __align__(16) char As[64 * 80];
    __shared__ __align__(16) char Bs[64 * 80];
    const int tid = threadIdx.x;
    const int wid = tid >> 6, lane = tid & 63;
    const int row0 = blockIdx.y * 64, col0 = blockIdx.x * 64;
    const int srow = tid >> 2, sslot = tid & 3;
    f32x4 acc[4];
    #pragma unroll
    for (int i = 0; i < 4; i++) acc[i] = (f32x4){0.f, 0.f, 0.f, 0.f};
    const int afoff = (wid * 16 + (lane & 15)) * 80 + (lane >> 4) * 16;
    for (int k0 = 0; k0 < K; k0 += 32) {
        b16x8 av, bv;
        if (AF32) {
            const float* Af = (const float*)Av + (size_t)(row0 + srow) * K + k0 + sslot * 8;
            float4 a0 = *(const float4*)Af;
            float4 a1 = *(const float4*)(Af + 4);
            av[0]=(short)f2b(a0.x); av[1]=(short)f2b(a0.y); av[2]=(short)f2b(a0.z); av[3]=(short)f2b(a0.w);
            av[4]=(short)f2b(a1.x); av[5]=(short)f2b(a1.y); av[6]=(short)f2b(a1.z); av[7]=(short)f2b(a1.w);
        } else {
            av = *(const b16x8*)((const unsigned short*)Av + (size_t)(row0 + srow) * K + k0 + sslot * 8);
        }
        bv = *(const b16x8*)(BTp + (size_t)(col0 + srow) * K + k0 + sslot * 8);
        __syncthreads();
        *(b16x8*)(As + srow * 80 + sslot * 16) = av;
        *(b16x8*)(Bs + srow * 80 + sslot * 16) = bv;
        __syncthreads();
        b16x8 af = *(const b16x8*)(As + afoff);
        #pragma unroll
        for (int ct = 0; ct < 4; ct++) {
            b16x8 bf = *(const b16x8*)(Bs + (ct * 16 + (lane & 15)) * 80 + (lane >> 4) * 16);
            acc[ct] = __builtin_amdgcn_mfma_f32_16x16x32_bf16(af, bf, acc[ct], 0, 0, 0);
        }
    }
    const int orow = row0 + wid * 16 + (lane >> 4) * 4;
    #pragma unroll
    for (int ct = 0; ct < 4; ct++) {
        int col = col0 + ct * 16 + (lane & 15);
        float bb = bias ? bias[col] : 0.f;
        #pragma unroll
        for (int r = 0; r < 4; r++) {
            float v = acc[ct][r] + bb;
            if (ACT == 1) v = 0.5f * v * (1.f + erff(v * 0.70710678118654752f));
            else if (ACT == 2) v = tanhf(v);
            size_t idx = (size_t)(orow + r) * N + col;
            if (OUTF) Cf[idx] = v;
            if (OUTB) Cb[idx] = f2b(v);
        }
    }
}

// ---------------- big MFMA GEMM: 128x128 tile, gload_lds, dbuf, swizzled ----------------
__global__ __launch_bounds__(256) void gemm_big_k(
        const unsigned short* __restrict__ Aptr, const unsigned short* __restrict__ Bptr,
        unsigned short* __restrict__ C, int N, int K)
{
    __shared__ __align__(16) unsigned short As[2][128 * 32];
    __shared__ __align__(16) unsigned short Bs[2][128 * 32];
    const int tid = threadIdx.x, w = tid >> 6, lane = tid & 63;
    const int l15 = lane & 15, lh = lane >> 4;
    const int nwg = gridDim.x * gridDim.y;
    const int orig = blockIdx.y * gridDim.x + blockIdx.x;
    const int q = nwg >> 3, r = nwg & 7;
    const int xcd = orig & 7, pos = orig >> 3;
    const int wgid = (xcd < r ? xcd * (q + 1) : r * (q + 1) + (xcd - r) * q) + pos;
    const int bx = wgid % gridDim.x, by = wgid / gridDim.x;
    const int row0 = by * 128, col0 = bx * 128;
    const int wr = w >> 1, wc = w & 1;
    const int slw = ((lane & 3) ^ ((lane >> 2) & 3) ^ ((lane >> 4) & 3)) & 3;
    const int pa  = (lh ^ (l15 & 3) ^ ((l15 >> 2) & 3)) & 3;
    f32x4 acc[4][4];
    #pragma unroll
    for (int i = 0; i < 4; i++)
        #pragma unroll
        for (int j = 0; j < 4; j++) acc[i][j] = (f32x4){0.f, 0.f, 0.f, 0.f};
    const int nkt = K >> 5;
    #pragma unroll
    for (int c = 0; c < 2; c++) {
        int ch = w * 2 + c, rr = ch * 16 + (lane >> 2);
        gload16(Aptr + (size_t)(row0 + rr) * K + slw * 8, &As[0][ch * 512]);
        gload16(Bptr + (size_t)(col0 + rr) * K + slw * 8, &Bs[0][ch * 512]);
    }
    __syncthreads();
    for (int kt = 0; kt < nkt; kt++) {
        const int buf = kt & 1;
        if (kt + 1 < nkt) {
            const int k0 = (kt + 1) << 5;
            #pragma unroll
            for (int c = 0; c < 2; c++) {
                int ch = w * 2 + c, rr = ch * 16 + (lane >> 2);
                gload16(Aptr + (size_t)(row0 + rr) * K + k0 + slw * 8, &As[buf ^ 1][ch * 512]);
                gload16(Bptr + (size_t)(col0 + rr) * K + k0 + slw * 8, &Bs[buf ^ 1][ch * 512]);
            }
        }
        b16x8 af[4], bf[4];
        #pragma unroll
        for (int f = 0; f < 4; f++) {
            af[f] = *(const b16x8*)(&As[buf][(wr * 64 + f * 16 + l15) * 32 + pa * 8]);
            bf[f] = *(const b16x8*)(&Bs[buf][(wc * 64 + f * 16 + l15) * 32 + pa * 8]);
        }
        #pragma unroll
        for (int i = 0; i < 4; i++)
            #pragma unroll
            for (int j = 0; j < 4; j++)
                acc[i][j] = __builtin_amdgcn_mfma_f32_16x16x32_bf16(af[i], bf[j], acc[i][j], 0, 0, 0);
        __syncthreads();
    }
    #pragma unroll
    for (int i = 0; i < 4; i++) {
        const int orow = row0 + wr * 64 + i * 16 + lh * 4;
        #pragma unroll
        for (int j = 0; j < 4; j++) {
            const int col = col0 + wc * 64 + j * 16 + l15;
            #pragma unroll
            for (int rr = 0; rr < 4; rr++)
                C[(size_t)(orow + rr) * N + col] = f2b(acc[i][j][rr]);
        }
    }
}

// ---------------- merged weight-prep ----------------
__device__ void tileT_dev(const float* __restrict__ W, unsigned short* __restrict__ WT,
        int K, int N, int bx, int by)
{
    __shared__ float s[32][33];
    const int n0 = bx * 32, k0 = by * 32;
    const int tx = threadIdx.x & 31, ty = threadIdx.x >> 5;
    #pragma unroll
    for (int i = 0; i < 32; i += 8) {
        int k = k0 + ty + i, n = n0 + tx;
        s[ty + i][tx] = (k < K && n < N) ? W[(size_t)k * N + n] : 0.f;
    }
    __syncthreads();
    #pragma unroll
    for (int i = 0; i < 32; i += 8) {
        int n = n0 + ty + i, k = k0 + tx;
        if (n < N && k < K) WT[(size_t)n * K + k] = f2b(s[tx][ty + i]);
    }
}

__global__ __launch_bounds__(256) void prep_all_k(
        const float* __restrict__ Wih, const float* __restrict__ Whh,
        const float* __restrict__ frW, const float* __restrict__ b1W1,
        const float* __restrict__ b1W2, const float* __restrict__ b2W1,
        const float* __restrict__ b2W2, const float* __restrict__ encW,
        const float* __restrict__ aW1, const float* __restrict__ cW1,
        const float* __restrict__ aW3, const float* __restrict__ aW2,
        const float* __restrict__ cW2, const float* __restrict__ ab1,
        const float* __restrict__ cb1, const float* __restrict__ ab2,
        const float* __restrict__ cb2, const float* __restrict__ emb,
        const float* __restrict__ img, const float* __restrict__ box,
        unsigned short* __restrict__ WihT, unsigned short* __restrict__ WhhT,
        unsigned short* __restrict__ frWT, unsigned short* __restrict__ b1W1T,
        unsigned short* __restrict__ b1W2T, unsigned short* __restrict__ b2W1T,
        unsigned short* __restrict__ b2W2T, unsigned short* __restrict__ encWT,
        unsigned short* __restrict__ W1cT, unsigned short* __restrict__ W2cT,
        unsigned short* __restrict__ WT3, float* __restrict__ b1c,
        float* __restrict__ b2c, unsigned short* __restrict__ embB,
        unsigned short* __restrict__ A0)
{
    int bid = blockIdx.x;
    const int tid = threadIdx.x;
    if (bid < 768) { tileT_dev(Wih, WihT, 512, 1536, bid % 48, bid / 48); return; }
    bid -= 768;
    if (bid < 768) { tileT_dev(Whh, WhhT, 512, 1536, bid % 48, bid / 48); return; }
    bid -= 768;
    if (bid < 1152) { tileT_dev(frW, frWT, 2304, 512, bid % 16, bid / 16); return; }
    bid -= 1152;
    if (bid < 256) { tileT_dev(b1W1, b1W1T, 512, 512, bid % 16, bid / 16); return; }
    bid -= 256;
    if (bid < 256) { tileT_dev(b1W2, b1W2T, 512, 512, bid % 16, bid / 16); return; }
    bid -= 256;
    if (bid < 256) { tileT_dev(b2W1, b2W1T, 512, 512, bid % 16, bid / 16); return; }
    bid -= 256;
    if (bid < 256) { tileT_dev(b2W2, b2W2T, 512, 512, bid % 16, bid / 16); return; }
    bid -= 256;
    if (bid < 256) { tileT_dev(encW, encWT, 512, 512, bid % 16, bid / 16); return; }
    bid -= 256;
    if (bid < 32) { tileT_dev(aW1, W1cT, 512, 64, bid % 2, bid / 2); return; }
    bid -= 32;
    if (bid < 32) { tileT_dev(cW1, W1cT + (size_t)64 * 512, 512, 64, bid % 2, bid / 2); return; }
    bid -= 32;
    if (bid < 626) { tileT_dev(aW3, WT3, 64, 10000, bid % 313, bid / 313); return; }
    bid -= 626;
    if (bid < 64) {
        int idx = bid * 256 + tid;
        int j = idx >> 7, k = idx & 127;
        float v = 0.f;
        if (j < 64 && k < 64) v = aW2[(size_t)k * 64 + j];
        else if (j >= 64 && k >= 64) v = cW2[(size_t)(k - 64) * 64 + (j - 64)];
        W2cT[idx] = f2b(v);
        return;
    }
    bid -= 64;
    if (bid < 1) {
        if (tid < 128) b1c[tid] = (tid < 64) ? ab1[tid] : cb1[tid - 64];
        else { int i = tid - 128; b2c[i] = (i < 64) ? ab2[i] : cb2[i - 64]; }
        return;
    }
    bid -= 1;
    if (bid < 5056) {
        int idx = bid * 256 + tid;
        int row = idx >> 7, c4 = (idx & 127) * 4;
        float4 v = {0.f, 0.f, 0.f, 0.f};
        if (row < Vv) v = *(const float4*)(emb + (size_t)row * 512 + c4);
        ushort4 o; o.x = f2b(v.x); o.y = f2b(v.y); o.z = f2b(v.z); o.w = f2b(v.w);
        *(ushort4*)(embB + (size_t)row * 512 + c4) = o;
        return;
    }
    bid -= 5056;
    {
        int idx = bid * 256 + tid;
        int row = idx / 576, c4 = (idx - row * 576) * 4;
        float4 v = (c4 < 2048) ? *(const float4*)(img + (size_t)row * 2048 + c4)
                               : *(const float4*)(box + (size_t)row * 256 + (c4 - 2048));
        ushort4 o; o.x = f2b(v.x); o.y = f2b(v.y); o.z = f2b(v.z); o.w = f2b(v.w);
        *(ushort4*)(A0 + (size_t)row * 2304 + c4) = o;
    }
}

// ---------------- LayerNorm over D=512 ----------------
__global__ __launch_bounds__(256) void ln_k(const float* __restrict__ Xa,
        const float* __restrict__ Xb, const float* __restrict__ g,
        const float* __restrict__ be, float* __restrict__ Y)
{
    const int row = blockIdx.x, tid = threadIdx.x;
    const size_t base = (size_t)row * 512;
    float a0 = Xa[base + tid], a1 = Xa[base + tid + 256];
    if (Xb) { a0 += Xb[base + tid]; a1 += Xb[base + tid + 256]; }
    float s = a0 + a1;
    #pragma unroll
    for (int o = 32; o; o >>= 1) s += __shfl_xor(s, o, 64);
    __shared__ float red[8];
    const int lane = tid & 63, wid = tid >> 6;
    if (!lane) red[wid] = s;
    __syncthreads();
    const float mean = (red[0] + red[1] + red[2] + red[3]) * (1.f / 512.f);
    const float d0 = a0 - mean, d1 = a1 - mean;
    float q = d0 * d0 + d1 * d1;
    #pragma unroll
    for (int o = 32; o; o >>= 1) q += __shfl_xor(q, o, 64);
    if (!lane) red[4 + wid] = q;
    __syncthreads();
    const float var = (red[4] + red[5] + red[6] + red[7]) * (1.f / 512.f);
    const float inv = rsqrtf(var + 1e-5f);
    float y0 = d0 * inv, y1 = d1 * inv;
    if (g) { y0 = y0 * g[tid] + be[tid]; y1 = y1 * g[tid + 256] + be[tid + 256]; }
    Y[base + tid] = y0; Y[base + tid + 256] = y1;
}

// ---------------- fused encoder residual block ----------------
// OUT = Rres + gelu(LN(P) @ W1 + b1) @ W2 + b2.  Row-local: 32 rows/block,
// grid 32, 256 thr = 4 waves; wave w: row-tile rt=w&1 (16 rows), col-half
// ch=w>>1 (256 cols = 16 MFMA col-tiles). A/t1 in LDS stride 520 (2-way banks),
// B double-buffered per 32-k chunk at 80B stride (proven gemm_bf_k layout).
__global__ __launch_bounds__(256) void eb_k(
        const float* __restrict__ P, const float* __restrict__ Rres,
        const unsigned short* __restrict__ W1T, const float* __restrict__ b1,
        const unsigned short* __restrict__ W2T, const float* __restrict__ b2,
        float* __restrict__ OUT)
{
    __shared__ __align__(16) unsigned short As[32 * 520];   // 33280 B
    __shared__ __align__(16) unsigned short Ts[32 * 520];   // 33280 B
    __shared__ __align__(16) unsigned short Bs[2][512 * 40];// 2x40960 B
    const int tid = threadIdx.x, w = tid >> 6, lane = tid & 63;
    const int l15 = lane & 15, lh = lane >> 4;
    const int rt = w & 1, ch = w >> 1;
    const int r0 = blockIdx.x * 32;

    // ---- LN(P) -> As (bf16). 8 threads/row, 64 floats each ----
    {
        const int row = tid >> 3, sub = tid & 7;
        const float4* Pr = (const float4*)(P + (size_t)(r0 + row) * 512 + sub * 64);
        float4 xv[16];
        float s = 0.f;
        #pragma unroll
        for (int i = 0; i < 16; i++) {
            xv[i] = Pr[i];
            s += xv[i].x + xv[i].y + xv[i].z + xv[i].w;
        }
        #pragma unroll
        for (int o = 1; o < 8; o <<= 1) s += __shfl_xor(s, o, 64);
        const float mean = s * (1.f / 512.f);
        float q = 0.f;
        #pragma unroll
        for (int i = 0; i < 16; i++) {
            float a = xv[i].x - mean, b = xv[i].y - mean,
                  c = xv[i].z - mean, d = xv[i].w - mean;
            q += a * a + b * b + c * c + d * d;
        }
        #pragma unroll
        for (int o = 1; o < 8; o <<= 1) q += __shfl_xor(q, o, 64);
        const float inv = rsqrtf(q * (1.f / 512.f) + 1e-5f);
        unsigned short* dst = As + row * 520 + sub * 64;
        #pragma unroll
        for (int j = 0; j < 8; j++) {
            float4 u = xv[2 * j], v = xv[2 * j + 1];
            b16x8 o8;
            o8[0] = (short)f2b((u.x - mean) * inv); o8[1] = (short)f2b((u.y - mean) * inv);
            o8[2] = (short)f2b((u.z - mean) * inv); o8[3] = (short)f2b((u.w - mean) * inv);
            o8[4] = (short)f2b((v.x - mean) * inv); o8[5] = (short)f2b((v.y - mean) * inv);
            o8[6] = (short)f2b((v.z - mean) * inv); o8[7] = (short)f2b((v.w - mean) * inv);
            *(b16x8*)(dst + j * 8) = o8;
        }
    }

    f32x4 acc[16];
    const int stcol0 = tid >> 2, stslot = (tid & 3) * 8;

    // ================= GEMM1: t1 = gelu(As @ W1 + b1) =================
    #pragma unroll
    for (int i = 0; i < 16; i++) acc[i] = (f32x4){0.f, 0.f, 0.f, 0.f};
    #pragma unroll
    for (int i = 0; i < 8; i++) {   // stage k0=0 into buf0
        int col = i * 64 + stcol0;
        *(b16x8*)(&Bs[0][col * 40 + stslot]) = *(const b16x8*)(W1T + (size_t)col * 512 + stslot);
    }
    __syncthreads();
    for (int kt = 0; kt < 16; kt++) {
        const int buf = kt & 1;
        if (kt < 15) {
            const int k0 = (kt + 1) * 32;
            #pragma unroll
            for (int i = 0; i < 8; i++) {
                int col = i * 64 + stcol0;
                *(b16x8*)(&Bs[buf ^ 1][col * 40 + stslot]) =
                    *(const b16x8*)(W1T + (size_t)col * 512 + k0 + stslot);
            }
        }
        b16x8 af = *(const b16x8*)(As + (rt * 16 + l15) * 520 + kt * 32 + lh * 8);
        #pragma unroll
        for (int ct = 0; ct < 16; ct++) {
            b16x8 bf = *(const b16x8*)(&Bs[buf][(ch * 256 + ct * 16 + l15) * 40 + lh * 8]);
            acc[ct] = __builtin_amdgcn_mfma_f32_16x16x32_bf16(af, bf, acc[ct], 0, 0, 0);
        }
        __syncthreads();
    }
    #pragma unroll
    for (int ct = 0; ct < 16; ct++) {
        const int col = ch * 256 + ct * 16 + l15;
        const float bb = b1[col];
        #pragma unroll
        for (int reg = 0; reg < 4; reg++) {
            float v = acc[ct][reg] + bb;
            v = 0.5f * v * (1.f + erff(v * 0.70710678118654752f));
            Ts[(rt * 16 + lh * 4 + reg) * 520 + col] = f2b(v);
        }
    }
    __syncthreads();

    // ================= GEMM2: OUT = Ts @ W2 + b2 + R =================
    #pragma unroll
    for (int i = 0; i < 16; i++) acc[i] = (f32x4){0.f, 0.f, 0.f, 0.f};
    #pragma unroll
    for (int i = 0; i < 8; i++) {
        int col = i * 64 + stcol0;
        *(b16x8*)(&Bs[0][col * 40 + stslot]) = *(const b16x8*)(W2T + (size_t)col * 512 + stslot);
    }
    __syncthreads();
    for (int kt = 0; kt < 16; kt++) {
        const int buf = kt & 1;
        if (kt < 15) {
            const int k0 = (kt + 1) * 32;
            #pragma unroll
            for (int i = 0; i < 8; i++) {
                int col = i * 64 + stcol0;
                *(b16x8*)(&Bs[buf ^ 1][col * 40 + stslot]) =
                    *(const b16x8*)(W2T + (size_t)col * 512 + k0 + stslot);
            }
        }
        b16x8 af = *(const b16x8*)(Ts + (rt * 16 + l15) * 520 + kt * 32 + lh * 8);
        #pragma unroll
        for (int ct = 0; ct < 16; ct++) {
            b16x8 bf = *(const b16x8*)(&Bs[buf][(ch * 256 + ct * 16 + l15) * 40 + lh * 8]);
            acc[ct] = __builtin_amdgcn_mfma_f32_16x16x32_bf16(af, bf, acc[ct], 0, 0, 0);
        }
        __syncthreads();
    }
    #pragma unroll
    for (int ct = 0; ct < 16; ct++) {
        const int col = ch * 256 + ct * 16 + l15;
        const float bb = b2[col];
        #pragma unroll
        for (int reg = 0; reg < 4; reg++) {
            const int row = r0 + rt * 16 + lh * 4 + reg;
            OUT[(size_t)row * 512 + col] = acc[ct][reg] + bb + Rres[(size_t)row * 512 + col];
        }
    }
}

// ---------------- one GRU step: A preloaded to regs, B via gload_lds ----------------
__global__ __launch_bounds__(256) void gru_step3_k(
        const unsigned short* __restrict__ Hprev,  // [1024][512] bf16
        const unsigned short* __restrict__ WihT,   // [1536][512] bf16
        const float* __restrict__ bih, const float* __restrict__ bhh,
        const unsigned short* __restrict__ GHemb,  // [10112][1536] bf16 (no bias)
        const float* __restrict__ emb, const int* __restrict__ acts, int t,
        unsigned short* __restrict__ Hout)
{
    __shared__ __align__(16) unsigned short sB[48 * 512];   // 49152 B
    const int tid = threadIdx.x, w = tid >> 6, lane = tid & 63;
    const int l15 = lane & 15, lh = lane >> 4;
    const int d0 = blockIdx.x * 16;
    const int rows0 = blockIdx.y * 64 + w * 16;
    const unsigned short* Arow = Hprev + (size_t)(rows0 + l15) * 512 + lh * 8;
    b16x8 a[16];
    #pragma unroll
    for (int kk = 0; kk < 16; kk++) a[kk] = *(const b16x8*)(Arow + kk * 32);
    #pragma unroll
    for (int c = 0; c < 12; c++) {
        const int ch = w * 12 + c;
        const int g = ch >> 4, col = ch & 15;
        const int sl = lane ^ (ch & 7);
        gload16(WihT + (size_t)(g * 512 + d0 + col) * 512 + sl * 8, &sB[ch * 512]);
    }
    __syncthreads();
    f32x4 ar = (f32x4){0.f,0.f,0.f,0.f}, az = ar, an = ar;
    #pragma unroll
    for (int kk = 0; kk < 16; kk++) {
        const int sl = ((kk * 4 + lh) ^ (l15 & 7));
        b16x8 b0 = *(const b16x8*)(&sB[(l15) * 512 + sl * 8]);
        b16x8 b1 = *(const b16x8*)(&sB[(16 + l15) * 512 + sl * 8]);
        b16x8 b2 = *(const b16x8*)(&sB[(32 + l15) * 512 + sl * 8]);
        ar = __builtin_amdgcn_mfma_f32_16x16x32_bf16(a[kk], b0, ar, 0, 0, 0);
        az = __builtin_amdgcn_mfma_f32_16x16x32_bf16(a[kk], b1, az, 0, 0, 0);
        an = __builtin_amdgcn_mfma_f32_16x16x32_bf16(a[kk], b2, an, 0, 0, 0);
    }
    const int d = d0 + l15;
    const float bi0 = bih[d], bi1 = bih[512 + d], bi2 = bih[1024 + d];
    const float bh0 = bhh[d], bh1 = bhh[512 + d], bh2 = bhh[1024 + d];
    #pragma unroll
    for (int reg = 0; reg < 4; reg++) {
        const int row = rows0 + lh * 4 + reg;
        float hr = bh0, hz = bh1, hn = bh2, ix = 0.f;
        if (t) {
            const int ap = acts[row * Tlen + t - 1];
            const size_t gb = (size_t)ap * 1536;
            hr += b2f(GHemb[gb + d]);
            hz += b2f(GHemb[gb + 512 + d]);
            hn += b2f(GHemb[gb + 1024 + d]);
            ix = emb[(size_t)ap * 512 + d];
        }
        const float rr = fast_sig(ar[reg] + bi0 + hr);
        const float zz = fast_sig(az[reg] + bi1 + hz);
        const float nn = fast_tanh(an[reg] + bi2 + rr * hn);
        Hout[(size_t)row * 512 + d] = f2b((1.f - zz) * nn + zz * ix);
    }
}

// ---------------- logits: V-split MFMA + partial exp-sums ----------------
__global__ __launch_bounds__(256) void logits3_k(const unsigned short* __restrict__ A2b,
        const unsigned short* __restrict__ WT3, const float* __restrict__ b3,
        const float* __restrict__ wmask, float* __restrict__ Spart,
        float* __restrict__ Wmpart)
{
    __shared__ __align__(16) char Bs[64 * 144];
    __shared__ float bmS[64];
    const int tid = threadIdx.x, wid = tid >> 6, lane = tid & 63;
    const int r0 = blockIdx.x * 64;
    const int c0 = blockIdx.y * 640;
    const int cend = (c0 + 640 < 5056) ? c0 + 640 : 5056;
    const size_t abase = (size_t)(r0 + wid * 16 + (lane & 15)) * 128 + (lane >> 4) * 8;
    const b16x8 af0 = *(const b16x8*)(A2b + abase);
    const b16x8 af1 = *(const b16x8*)(A2b + abase + 32);
    float S[4] = {0.f, 0.f, 0.f, 0.f}, Wm[4] = {0.f, 0.f, 0.f, 0.f};
    for (int cc = c0; cc < cend; cc += 64) {
        __syncthreads();
        #pragma unroll
        for (int i = 0; i < 2; i++) {
            int e = tid + i * 256;
            int rr = e >> 3, slot = e & 7;
            b16x8 wv = *(const b16x8*)(WT3 + (size_t)(cc + rr) * 64 + slot * 8);
            *(b16x8*)(Bs + rr * 144 + slot * 16) = wv;
        }
        if (tid < 64) bmS[tid] = b3[cc + tid] + wmask[cc + tid];
        __syncthreads();
        #pragma unroll
        for (int ct = 0; ct < 4; ct++) {
            const int colb = (ct * 16 + (lane & 15)) * 144 + (lane >> 4) * 16;
            b16x8 bf0 = *(const b16x8*)(Bs + colb);
            b16x8 bf1 = *(const b16x8*)(Bs + colb + 64);
            f32x4 acc = (f32x4){0.f, 0.f, 0.f, 0.f};
            acc = __builtin_amdgcn_mfma_f32_16x16x32_bf16(af0, bf0, acc, 0, 0, 0);
            acc = __builtin_amdgcn_mfma_f32_16x16x32_bf16(af1, bf1, acc, 0, 0, 0);
            const float bm = bmS[ct * 16 + (lane & 15)];
            #pragma unroll
            for (int r = 0; r < 4; r++) {
                float l = acc[r] + bm;
                float e = __expf(l);
                S[r] += e;
                Wm[r] = fmaf(e, l, Wm[r]);
            }
        }
    }
    #pragma unroll
    for (int r = 0; r < 4; r++) {
        float s = S[r], w = Wm[r];
        #pragma unroll
        for (int o = 1; o < 16; o <<= 1) {
            s += __shfl_xor(s, o, 64);
            w += __shfl_xor(w, o, 64);
        }
        if ((lane & 15) == 0) {
            int row = r0 + wid * 16 + (lane >> 4) * 4 + r;
            Spart[blockIdx.y * BT + row] = s;
            Wmpart[blockIdx.y * BT + row] = w;
        }
    }
}

// ---------------- merged tail: entropy / logp / value / actions ----------------
__global__ __launch_bounds__(256) void tail_k(const float* __restrict__ Spart,
        const float* __restrict__ Wmpart, const unsigned short* __restrict__ L2b,
        const unsigned short* __restrict__ WT3, const float* __restrict__ b3,
        const float* __restrict__ wmask, const int* __restrict__ acts,
        const float* __restrict__ cw3, const float* __restrict__ cb3,
        float* __restrict__ out)
{
    const int bid = blockIdx.x, tid = threadIdx.x;
    if (bid < 80) {
        const int rt = bid * 256 + tid;
        float s = 0.f, wm = 0.f;
        #pragma unroll
        for (int j = 0; j < 8; j++) { s += Spart[j * BT + rt]; wm += Wmpart[j * BT + rt]; }
        const float l = logf(s);
        const int t = rt >> 10, b = rt & 1023;
        out[2 * BT + b * Tlen + t] = l - wm / s;
    } else if (bid < 160) {
        const int rt = (bid - 80) * 256 + tid;
        float s = 0.f;
        #pragma unroll
        for (int j = 0; j < 8; j++) s += Spart[j * BT + rt];
        const int t = rt >> 10, b = rt & 1023;
        const int a = acts[b * Tlen + t];
        const unsigned short* ar = L2b + (size_t)rt * 128;
        const unsigned short* wr = WT3 + (size_t)a * 64;
        float dot = 0.f;
        #pragma unroll 16
        for (int k = 0; k < 64; k++) dot = fmaf(b2f(ar[k]), b2f(wr[k]), dot);
        out[BT + b * Tlen + t] = dot + b3[a] + wmask[a] - logf(s);
    } else if (bid < 240) {
        const int rt = (bid - 160) * 256 + tid;
        const unsigned short* c = L2b + (size_t)rt * 128 + 64;
        float s = cb3[0];
        #pragma unroll 16
        for (int k = 0; k < 64; k++) s = fmaf(b2f(c[k]), cw3[k], s);
        const int t = rt >> 10, b = rt & 1023;
        out[3 * BT + b * Tlen + t] = s;
    } else {
        const int rt = (bid - 240) * 256 + tid;
        out[rt] = (float)acts[rt];
    }
}

extern "C" void kernel_launch(void* const* d_in, const int* in_sizes, int n_in,
                              void* d_out, int out_size, void* d_ws, size_t ws_size,
                              hipStream_t stream)
{
    const float* img  = (const float*)d_in[0];
    const float* box  = (const float*)d_in[1];
    const int*   acts = (const int*)d_in[2];
    const float* fr_W = (const float*)d_in[3];
    const float* fr_b = (const float*)d_in[4];
    const float* b1W1 = (const float*)d_in[5];
    const float* b1b1 = (const float*)d_in[6];
    const float* b1W2 = (const float*)d_in[7];
    const float* b1b2 = (const float*)d_in[8];
    const float* b2W1 = (const float*)d_in[9];
    const float* b2b1 = (const float*)d_in[10];
    const float* b2W2 = (const float*)d_in[11];
    const float* b2b2 = (const float*)d_in[12];
    const float* lng  = (const float*)d_in[13];
    const float* lnb  = (const float*)d_in[14];
    const float* encW = (const float*)d_in[15];
    const float* encb = (const float*)d_in[16];
    const float* emb  = (const float*)d_in[17];
    const float* Wih  = (const float*)d_in[18];
    const float* bih  = (const float*)d_in[19];
    const float* Whh  = (const float*)d_in[20];
    const float* bhh  = (const float*)d_in[21];
    const float* aW1  = (const float*)d_in[22];
    const float* ab1  = (const float*)d_in[23];
    const float* aW2  = (const float*)d_in[24];
    const float* ab2  = (const float*)d_in[25];
    const float* aW3  = (const float*)d_in[26];
    const float* ab3  = (const float*)d_in[27];
    const float* cW1  = (const float*)d_in[28];
    const float* cb1  = (const float*)d_in[29];
    const float* cW2  = (const float*)d_in[30];
    const float* cb2  = (const float*)d_in[31];
    const float* cW3  = (const float*)d_in[32];
    const float* cb3  = (const float*)d_in[33];
    const float* wmask= (const float*)d_in[34];
    float* out = (float*)d_out;

    // ---- workspace ----
    char* w = (char*)d_ws;
    unsigned short* WihT  = (unsigned short*)w; w += (size_t)786432 * 2;
    unsigned short* WhhT  = (unsigned short*)w; w += (size_t)786432 * 2;
    unsigned short* frWT  = (unsigned short*)w; w += (size_t)1179648 * 2;
    unsigned short* b1W1T = (unsigned short*)w; w += (size_t)262144 * 2;
    unsigned short* b1W2T = (unsigned short*)w; w += (size_t)262144 * 2;
    unsigned short* b2W1T = (unsigned short*)w; w += (size_t)262144 * 2;
    unsigned short* b2W2T = (unsigned short*)w; w += (size_t)262144 * 2;
    unsigned short* encWT = (unsigned short*)w; w += (size_t)262144 * 2;
    unsigned short* W1cT  = (unsigned short*)w; w += (size_t)65536 * 2;
    unsigned short* W2cT  = (unsigned short*)w; w += (size_t)16384 * 2;
    unsigned short* WT3   = (unsigned short*)w; w += (size_t)640000 * 2;
    float* b1c = (float*)w;                     w += 128 * 4;
    float* b2c = (float*)w;                     w += 128 * 4;
    unsigned short* embB  = (unsigned short*)w; w += (size_t)10112 * 512 * 2;
    unsigned short* GHemb = (unsigned short*)w; w += (size_t)10112 * 1536 * 2;
    unsigned short* HALLb = (unsigned short*)w; w += (size_t)10485760 * 2;
    unsigned short* L1b   = (unsigned short*)w; w += (size_t)2621440 * 2;
    unsigned short* L2b   = (unsigned short*)w; w += (size_t)2621440 * 2;
    unsigned short* HB0   = (unsigned short*)w; w += (size_t)524288 * 2;
    float* Spart = (float*)w;                   w += (size_t)8 * BT * 4;
    float* Wmpart= (float*)w;                   w += (size_t)8 * BT * 4;
    char* arena = w;                            w += (size_t)20971520;

    unsigned short* A0 = (unsigned short*)arena;
    float* Xe  = (float*)(arena + 4718592);
    float* S1  = Xe + 524288;
    float* S2  = S1 + 524288;
    float* Ye  = S2 + 524288;

    const dim3 blk(256);

    // ---- all weight prep in one launch ----
    prep_all_k<<<12083, blk, 0, stream>>>(Wih, Whh, fr_W, b1W1, b1W2, b2W1, b2W2,
            encW, aW1, cW1, aW3, aW2, cW2, ab1, cb1, ab2, cb2, emb, img, box,
            WihT, WhhT, frWT, b1W1T, b1W2T, b2W1T, b2W2T, encWT, W1cT, W2cT,
            WT3, b1c, b2c, embB, A0);

    // ---- GHemb = embB @ Whh^T over vocab ----
    gemm_big_k<<<dim3(12, 79), blk, 0, stream>>>(embB, WhhT, GHemb, 1536, 512);

    // ---- encoder: gemm_fr -> eb1 -> eb2 -> ln -> gemm_enc (5 launches) ----
    gemm_bf_k<0, 1, 0, 0><<<dim3(8, 16), blk, 0, stream>>>(A0, frWT, fr_b, Xe, nullptr, 1024, 512, 2304);
    eb_k<<<32, blk, 0, stream>>>(Xe, Xe, b1W1T, b1b1, b1W2T, b1b2, S1);
    eb_k<<<32, blk, 0, stream>>>(S1, Xe, b2W1T, b2b1, b2W2T, b2b2, S2);
    ln_k<<<1024, blk, 0, stream>>>(S2, nullptr, lng, lnb, Ye);
    gemm_bf_k<0, 0, 1, 1><<<dim3(8, 16), blk, 0, stream>>>(Ye, encWT, encb, nullptr, HB0, 1024, 512, 512);

    // ---- GRU scan: one fused kernel per step ----
    for (int t = 0; t < Tlen; ++t) {
        const unsigned short* Hprev = t ? HALLb + (size_t)(t - 1) * 524288 : HB0;
        gru_step3_k<<<dim3(32, 16), blk, 0, stream>>>(Hprev, WihT, bih, bhh,
                GHemb, emb, acts, t, HALLb + (size_t)t * 524288);
    }

    // ---- fused heads ----
    gemm_bf_k<2, 0, 1, 0><<<dim3(2, 320), blk, 0, stream>>>(HALLb, W1cT, b1c,
            nullptr, L1b, BT, 128, 512);
    gemm_bf_k<2, 0, 1, 0><<<dim3(2, 320), blk, 0, stream>>>(L1b, W2cT, b2c,
            nullptr, L2b, BT, 128, 128);
    logits3_k<<<dim3(320, 8), blk, 0, stream>>>(L2b, WT3, ab3, wmask, Spart, Wmpart);
    tail_k<<<320, blk, 0, stream>>>(Spart, Wmpart, L2b, WT3, ab3, wmask, acts,
            cW3, cb3, out);
}

// Round 9
// 423.157 us; speedup vs baseline: 2.7510x; 1.0224x over previous
//
#include <hip/hip_runtime.h>
#include <math.h>

#define Tlen 20
#define Vv 10000
#define BT 20480

typedef __attribute__((ext_vector_type(8))) short b16x8;
typedef __attribute__((ext_vector_type(4))) float f32x4;

__device__ __forceinline__ unsigned short f2b(float f){
    union { float f; unsigned u; } v; v.f = f;
    unsigned r = v.u + 0x7FFFu + ((v.u >> 16) & 1u);
    return (unsigned short)(r >> 16);
}
__device__ __forceinline__ float b2f(unsigned short h){
    union { unsigned u; float f; } v; v.u = ((unsigned)h) << 16;
    return v.f;
}
__device__ __forceinline__ void gload16(const void* g, void* l){
    __builtin_amdgcn_global_load_lds(
        (const __attribute__((address_space(1))) unsigned int*)g,
        (__attribute__((address_space(3))) unsigned int*)l, 16, 0, 0);
}
__device__ __forceinline__ float fast_sig(float x){ return 1.f / (1.f + __expf(-x)); }
__device__ __forceinline__ float fast_tanh(float x){ return 1.f - 2.f / (__expf(2.f * x) + 1.f); }

// ---------------- bf16 MFMA GEMM 64x64 tile (encoder/heads) ----------------
template<int ACT, int OUTF, int OUTB, int AF32>
__global__ __launch_bounds__(256) void gemm_bf_k(
        const void* __restrict__ Av, const unsigned short* __restrict__ BTp,
        const float* __restrict__ bias, float* __restrict__ Cf,
        unsigned short* __restrict__ Cb, int M, int N, int K)
{
    __shared__ __align__(16) char As[64 * 80];
    __shared__ __align__(16) char Bs[64 * 80];
    const int tid = threadIdx.x;
    const int wid = tid >> 6, lane = tid & 63;
    const int row0 = blockIdx.y * 64, col0 = blockIdx.x * 64;
    const int srow = tid >> 2, sslot = tid & 3;
    f32x4 acc[4];
    #pragma unroll
    for (int i = 0; i < 4; i++) acc[i] = (f32x4){0.f, 0.f, 0.f, 0.f};
    const int afoff = (wid * 16 + (lane & 15)) * 80 + (lane >> 4) * 16;
    for (int k0 = 0; k0 < K; k0 += 32) {
        b16x8 av, bv;
        if (AF32) {
            const float* Af = (const float*)Av + (size_t)(row0 + srow) * K + k0 + sslot * 8;
            float4 a0 = *(const float4*)Af;
            float4 a1 = *(const float4*)(Af + 4);
            av[0]=(short)f2b(a0.x); av[1]=(short)f2b(a0.y); av[2]=(short)f2b(a0.z); av[3]=(short)f2b(a0.w);
            av[4]=(short)f2b(a1.x); av[5]=(short)f2b(a1.y); av[6]=(short)f2b(a1.z); av[7]=(short)f2b(a1.w);
        } else {
            av = *(const b16x8*)((const unsigned short*)Av + (size_t)(row0 + srow) * K + k0 + sslot * 8);
        }
        bv = *(const b16x8*)(BTp + (size_t)(col0 + srow) * K + k0 + sslot * 8);
        __syncthreads();
        *(b16x8*)(As + srow * 80 + sslot * 16) = av;
        *(b16x8*)(Bs + srow * 80 + sslot * 16) = bv;
        __syncthreads();
        b16x8 af = *(const b16x8*)(As + afoff);
        #pragma unroll
        for (int ct = 0; ct < 4; ct++) {
            b16x8 bf = *(const b16x8*)(Bs + (ct * 16 + (lane & 15)) * 80 + (lane >> 4) * 16);
            acc[ct] = __builtin_amdgcn_mfma_f32_16x16x32_bf16(af, bf, acc[ct], 0, 0, 0);
        }
    }
    const int orow = row0 + wid * 16 + (lane >> 4) * 4;
    #pragma unroll
    for (int ct = 0; ct < 4; ct++) {
        int col = col0 + ct * 16 + (lane & 15);
        float bb = bias ? bias[col] : 0.f;
        #pragma unroll
        for (int r = 0; r < 4; r++) {
            float v = acc[ct][r] + bb;
            if (ACT == 1) v = 0.5f * v * (1.f + erff(v * 0.70710678118654752f));
            else if (ACT == 2) v = tanhf(v);
            size_t idx = (size_t)(orow + r) * N + col;
            if (OUTF) Cf[idx] = v;
            if (OUTB) Cb[idx] = f2b(v);
        }
    }
}

// ---------------- big MFMA GEMM: 128x128 tile, gload_lds, dbuf, swizzled ----------------
__global__ __launch_bounds__(256) void gemm_big_k(
        const unsigned short* __restrict__ Aptr, const unsigned short* __restrict__ Bptr,
        unsigned short* __restrict__ C, int N, int K)
{
    __shared__ __align__(16) unsigned short As[2][128 * 32];
    __shared__ __align__(16) unsigned short Bs[2][128 * 32];
    const int tid = threadIdx.x, w = tid >> 6, lane = tid & 63;
    const int l15 = lane & 15, lh = lane >> 4;
    const int nwg = gridDim.x * gridDim.y;
    const int orig = blockIdx.y * gridDim.x + blockIdx.x;
    const int q = nwg >> 3, r = nwg & 7;
    const int xcd = orig & 7, pos = orig >> 3;
    const int wgid = (xcd < r ? xcd * (q + 1) : r * (q + 1) + (xcd - r) * q) + pos;
    const int bx = wgid % gridDim.x, by = wgid / gridDim.x;
    const int row0 = by * 128, col0 = bx * 128;
    const int wr = w >> 1, wc = w & 1;
    const int slw = ((lane & 3) ^ ((lane >> 2) & 3) ^ ((lane >> 4) & 3)) & 3;
    const int pa  = (lh ^ (l15 & 3) ^ ((l15 >> 2) & 3)) & 3;
    f32x4 acc[4][4];
    #pragma unroll
    for (int i = 0; i < 4; i++)
        #pragma unroll
        for (int j = 0; j < 4; j++) acc[i][j] = (f32x4){0.f, 0.f, 0.f, 0.f};
    const int nkt = K >> 5;
    #pragma unroll
    for (int c = 0; c < 2; c++) {
        int ch = w * 2 + c, rr = ch * 16 + (lane >> 2);
        gload16(Aptr + (size_t)(row0 + rr) * K + slw * 8, &As[0][ch * 512]);
        gload16(Bptr + (size_t)(col0 + rr) * K + slw * 8, &Bs[0][ch * 512]);
    }
    __syncthreads();
    for (int kt = 0; kt < nkt; kt++) {
        const int buf = kt & 1;
        if (kt + 1 < nkt) {
            const int k0 = (kt + 1) << 5;
            #pragma unroll
            for (int c = 0; c < 2; c++) {
                int ch = w * 2 + c, rr = ch * 16 + (lane >> 2);
                gload16(Aptr + (size_t)(row0 + rr) * K + k0 + slw * 8, &As[buf ^ 1][ch * 512]);
                gload16(Bptr + (size_t)(col0 + rr) * K + k0 + slw * 8, &Bs[buf ^ 1][ch * 512]);
            }
        }
        b16x8 af[4], bf[4];
        #pragma unroll
        for (int f = 0; f < 4; f++) {
            af[f] = *(const b16x8*)(&As[buf][(wr * 64 + f * 16 + l15) * 32 + pa * 8]);
            bf[f] = *(const b16x8*)(&Bs[buf][(wc * 64 + f * 16 + l15) * 32 + pa * 8]);
        }
        #pragma unroll
        for (int i = 0; i < 4; i++)
            #pragma unroll
            for (int j = 0; j < 4; j++)
                acc[i][j] = __builtin_amdgcn_mfma_f32_16x16x32_bf16(af[i], bf[j], acc[i][j], 0, 0, 0);
        __syncthreads();
    }
    #pragma unroll
    for (int i = 0; i < 4; i++) {
        const int orow = row0 + wr * 64 + i * 16 + lh * 4;
        #pragma unroll
        for (int j = 0; j < 4; j++) {
            const int col = col0 + wc * 64 + j * 16 + l15;
            #pragma unroll
            for (int rr = 0; rr < 4; rr++)
                C[(size_t)(orow + rr) * N + col] = f2b(acc[i][j][rr]);
        }
    }
}

// ---------------- merged weight-prep ----------------
__device__ void tileT_dev(const float* __restrict__ W, unsigned short* __restrict__ WT,
        int K, int N, int bx, int by)
{
    __shared__ float s[32][33];
    const int n0 = bx * 32, k0 = by * 32;
    const int tx = threadIdx.x & 31, ty = threadIdx.x >> 5;
    #pragma unroll
    for (int i = 0; i < 32; i += 8) {
        int k = k0 + ty + i, n = n0 + tx;
        s[ty + i][tx] = (k < K && n < N) ? W[(size_t)k * N + n] : 0.f;
    }
    __syncthreads();
    #pragma unroll
    for (int i = 0; i < 32; i += 8) {
        int n = n0 + ty + i, k = k0 + tx;
        if (n < N && k < K) WT[(size_t)n * K + k] = f2b(s[tx][ty + i]);
    }
}

__global__ __launch_bounds__(256) void prep_all_k(
        const float* __restrict__ Wih, const float* __restrict__ Whh,
        const float* __restrict__ frW, const float* __restrict__ b1W1,
        const float* __restrict__ b1W2, const float* __restrict__ b2W1,
        const float* __restrict__ b2W2, const float* __restrict__ encW,
        const float* __restrict__ aW1, const float* __restrict__ cW1,
        const float* __restrict__ aW3, const float* __restrict__ aW2,
        const float* __restrict__ cW2, const float* __restrict__ ab1,
        const float* __restrict__ cb1, const float* __restrict__ ab2,
        const float* __restrict__ cb2, const float* __restrict__ emb,
        const float* __restrict__ img, const float* __restrict__ box,
        unsigned short* __restrict__ WihT, unsigned short* __restrict__ WhhT,
        unsigned short* __restrict__ frWT, unsigned short* __restrict__ b1W1T,
        unsigned short* __restrict__ b1W2T, unsigned short* __restrict__ b2W1T,
        unsigned short* __restrict__ b2W2T, unsigned short* __restrict__ encWT,
        unsigned short* __restrict__ W1cT, unsigned short* __restrict__ W2cT,
        unsigned short* __restrict__ WT3, float* __restrict__ b1c,
        float* __restrict__ b2c, unsigned short* __restrict__ embB,
        unsigned short* __restrict__ A0)
{
    int bid = blockIdx.x;
    const int tid = threadIdx.x;
    if (bid < 768) { tileT_dev(Wih, WihT, 512, 1536, bid % 48, bid / 48); return; }
    bid -= 768;
    if (bid < 768) { tileT_dev(Whh, WhhT, 512, 1536, bid % 48, bid / 48); return; }
    bid -= 768;
    if (bid < 1152) { tileT_dev(frW, frWT, 2304, 512, bid % 16, bid / 16); return; }
    bid -= 1152;
    if (bid < 256) { tileT_dev(b1W1, b1W1T, 512, 512, bid % 16, bid / 16); return; }
    bid -= 256;
    if (bid < 256) { tileT_dev(b1W2, b1W2T, 512, 512, bid % 16, bid / 16); return; }
    bid -= 256;
    if (bid < 256) { tileT_dev(b2W1, b2W1T, 512, 512, bid % 16, bid / 16); return; }
    bid -= 256;
    if (bid < 256) { tileT_dev(b2W2, b2W2T, 512, 512, bid % 16, bid / 16); return; }
    bid -= 256;
    if (bid < 256) { tileT_dev(encW, encWT, 512, 512, bid % 16, bid / 16); return; }
    bid -= 256;
    if (bid < 32) { tileT_dev(aW1, W1cT, 512, 64, bid % 2, bid / 2); return; }
    bid -= 32;
    if (bid < 32) { tileT_dev(cW1, W1cT + (size_t)64 * 512, 512, 64, bid % 2, bid / 2); return; }
    bid -= 32;
    if (bid < 626) { tileT_dev(aW3, WT3, 64, 10000, bid % 313, bid / 313); return; }
    bid -= 626;
    if (bid < 64) {
        int idx = bid * 256 + tid;
        int j = idx >> 7, k = idx & 127;
        float v = 0.f;
        if (j < 64 && k < 64) v = aW2[(size_t)k * 64 + j];
        else if (j >= 64 && k >= 64) v = cW2[(size_t)(k - 64) * 64 + (j - 64)];
        W2cT[idx] = f2b(v);
        return;
    }
    bid -= 64;
    if (bid < 1) {
        if (tid < 128) b1c[tid] = (tid < 64) ? ab1[tid] : cb1[tid - 64];
        else { int i = tid - 128; b2c[i] = (i < 64) ? ab2[i] : cb2[i - 64]; }
        return;
    }
    bid -= 1;
    if (bid < 5056) {
        int idx = bid * 256 + tid;
        int row = idx >> 7, c4 = (idx & 127) * 4;
        float4 v = {0.f, 0.f, 0.f, 0.f};
        if (row < Vv) v = *(const float4*)(emb + (size_t)row * 512 + c4);
        ushort4 o; o.x = f2b(v.x); o.y = f2b(v.y); o.z = f2b(v.z); o.w = f2b(v.w);
        *(ushort4*)(embB + (size_t)row * 512 + c4) = o;
        return;
    }
    bid -= 5056;
    {
        int idx = bid * 256 + tid;
        int row = idx / 576, c4 = (idx - row * 576) * 4;
        float4 v = (c4 < 2048) ? *(const float4*)(img + (size_t)row * 2048 + c4)
                               : *(const float4*)(box + (size_t)row * 256 + (c4 - 2048));
        ushort4 o; o.x = f2b(v.x); o.y = f2b(v.y); o.z = f2b(v.z); o.w = f2b(v.w);
        *(ushort4*)(A0 + (size_t)row * 2304 + c4) = o;
    }
}

// ---------------- LayerNorm over D=512 ----------------
__global__ __launch_bounds__(256) void ln_k(const float* __restrict__ Xa,
        const float* __restrict__ Xb, const float* __restrict__ g,
        const float* __restrict__ be, float* __restrict__ Y)
{
    const int row = blockIdx.x, tid = threadIdx.x;
    const size_t base = (size_t)row * 512;
    float a0 = Xa[base + tid], a1 = Xa[base + tid + 256];
    if (Xb) { a0 += Xb[base + tid]; a1 += Xb[base + tid + 256]; }
    float s = a0 + a1;
    #pragma unroll
    for (int o = 32; o; o >>= 1) s += __shfl_xor(s, o, 64);
    __shared__ float red[8];
    const int lane = tid & 63, wid = tid >> 6;
    if (!lane) red[wid] = s;
    __syncthreads();
    const float mean = (red[0] + red[1] + red[2] + red[3]) * (1.f / 512.f);
    const float d0 = a0 - mean, d1 = a1 - mean;
    float q = d0 * d0 + d1 * d1;
    #pragma unroll
    for (int o = 32; o; o >>= 1) q += __shfl_xor(q, o, 64);
    if (!lane) red[4 + wid] = q;
    __syncthreads();
    const float var = (red[4] + red[5] + red[6] + red[7]) * (1.f / 512.f);
    const float inv = rsqrtf(var + 1e-5f);
    float y0 = d0 * inv, y1 = d1 * inv;
    if (g) { y0 = y0 * g[tid] + be[tid]; y1 = y1 * g[tid + 256] + be[tid + 256]; }
    Y[base + tid] = y0; Y[base + tid + 256] = y1;
}

// ---------------- one GRU step: A preloaded, B via gload_lds, gathers prefetched ----------------
// grid (32,16): d0 = bx*16, rows0 = by*64 + w*16. Wave: 16 rows x 16 cols x 3 gates.
// All global gathers (A-frags, GHemb, emb) issue BEFORE the staging barrier so the
// vmcnt(0) drain hides them; epilogue is pure VALU.
__global__ __launch_bounds__(256) void gru_step3_k(
        const unsigned short* __restrict__ Hprev,  // [1024][512] bf16
        const unsigned short* __restrict__ WihT,   // [1536][512] bf16
        const float* __restrict__ bih, const float* __restrict__ bhh,
        const unsigned short* __restrict__ GHemb,  // [10112][1536] bf16 (no bias)
        const float* __restrict__ emb, const int* __restrict__ acts, int t,
        unsigned short* __restrict__ Hout)
{
    __shared__ __align__(16) unsigned short sB[48 * 512];   // 49152 B
    const int tid = threadIdx.x, w = tid >> 6, lane = tid & 63;
    const int l15 = lane & 15, lh = lane >> 4;
    const int d0 = blockIdx.x * 16;
    const int rows0 = blockIdx.y * 64 + w * 16;
    const int d = d0 + l15;
    // A-fragment preload (fills vmem queue, overlaps staging)
    const unsigned short* Arow = Hprev + (size_t)(rows0 + l15) * 512 + lh * 8;
    b16x8 a[16];
    #pragma unroll
    for (int kk = 0; kk < 16; kk++) a[kk] = *(const b16x8*)(Arow + kk * 32);
    // stage B: 48 rows x 1KB via gload_lds, source pre-swizzled by row&7
    #pragma unroll
    for (int c = 0; c < 12; c++) {
        const int ch = w * 12 + c;
        const int g = ch >> 4, col = ch & 15;
        const int sl = lane ^ (ch & 7);
        gload16(WihT + (size_t)(g * 512 + d0 + col) * 512 + sl * 8, &sB[ch * 512]);
    }
    // prefetch recurrence-independent gathers (hidden under the barrier's vmcnt drain)
    float hrv[4], hzv[4], hnv[4], ixv[4];
    #pragma unroll
    for (int reg = 0; reg < 4; reg++) {
        hrv[reg] = 0.f; hzv[reg] = 0.f; hnv[reg] = 0.f; ixv[reg] = 0.f;
        if (t) {
            const int row = rows0 + lh * 4 + reg;
            const int ap = acts[row * Tlen + t - 1];
            const size_t gb = (size_t)ap * 1536;
            hrv[reg] = b2f(GHemb[gb + d]);
            hzv[reg] = b2f(GHemb[gb + 512 + d]);
            hnv[reg] = b2f(GHemb[gb + 1024 + d]);
            ixv[reg] = emb[(size_t)ap * 512 + d];
        }
    }
    const float bi0 = bih[d], bi1 = bih[512 + d], bi2 = bih[1024 + d];
    const float bh0 = bhh[d], bh1 = bhh[512 + d], bh2 = bhh[1024 + d];
    __syncthreads();
    f32x4 ar = (f32x4){0.f,0.f,0.f,0.f}, az = ar, an = ar;
    #pragma unroll
    for (int kk = 0; kk < 16; kk++) {
        const int sl = ((kk * 4 + lh) ^ (l15 & 7));
        b16x8 b0 = *(const b16x8*)(&sB[(l15) * 512 + sl * 8]);
        b16x8 b1 = *(const b16x8*)(&sB[(16 + l15) * 512 + sl * 8]);
        b16x8 b2 = *(const b16x8*)(&sB[(32 + l15) * 512 + sl * 8]);
        ar = __builtin_amdgcn_mfma_f32_16x16x32_bf16(a[kk], b0, ar, 0, 0, 0);
        az = __builtin_amdgcn_mfma_f32_16x16x32_bf16(a[kk], b1, az, 0, 0, 0);
        an = __builtin_amdgcn_mfma_f32_16x16x32_bf16(a[kk], b2, an, 0, 0, 0);
    }
    #pragma unroll
    for (int reg = 0; reg < 4; reg++) {
        const int row = rows0 + lh * 4 + reg;
        const float rr = fast_sig(ar[reg] + bi0 + bh0 + hrv[reg]);
        const float zz = fast_sig(az[reg] + bi1 + bh1 + hzv[reg]);
        const float nn = fast_tanh(an[reg] + bi2 + bh2 + hnv[reg] * rr - bh2 * rr + bh2 * rr);
        // note: n = tanh(in + bi2 + r*(GH_n + bh2)); hnv holds GH_n (no bias)
        const float nn2 = fast_tanh(an[reg] + bi2 + rr * (hnv[reg] + bh2));
        (void)nn;
        Hout[(size_t)row * 512 + d] = f2b((1.f - zz) * nn2 + zz * ixv[reg]);
    }
}

// ---------------- logits: V-split MFMA + partial exp-sums ----------------
__global__ __launch_bounds__(256) void logits3_k(const unsigned short* __restrict__ A2b,
        const unsigned short* __restrict__ WT3, const float* __restrict__ b3,
        const float* __restrict__ wmask, float* __restrict__ Spart,
        float* __restrict__ Wmpart)
{
    __shared__ __align__(16) char Bs[64 * 144];
    __shared__ float bmS[64];
    const int tid = threadIdx.x, wid = tid >> 6, lane = tid & 63;
    const int r0 = blockIdx.x * 64;
    const int c0 = blockIdx.y * 640;
    const int cend = (c0 + 640 < 5056) ? c0 + 640 : 5056;
    const size_t abase = (size_t)(r0 + wid * 16 + (lane & 15)) * 128 + (lane >> 4) * 8;
    const b16x8 af0 = *(const b16x8*)(A2b + abase);
    const b16x8 af1 = *(const b16x8*)(A2b + abase + 32);
    float S[4] = {0.f, 0.f, 0.f, 0.f}, Wm[4] = {0.f, 0.f, 0.f, 0.f};
    for (int cc = c0; cc < cend; cc += 64) {
        __syncthreads();
        #pragma unroll
        for (int i = 0; i < 2; i++) {
            int e = tid + i * 256;
            int rr = e >> 3, slot = e & 7;
            b16x8 wv = *(const b16x8*)(WT3 + (size_t)(cc + rr) * 64 + slot * 8);
            *(b16x8*)(Bs + rr * 144 + slot * 16) = wv;
        }
        if (tid < 64) bmS[tid] = b3[cc + tid] + wmask[cc + tid];
        __syncthreads();
        #pragma unroll
        for (int ct = 0; ct < 4; ct++) {
            const int colb = (ct * 16 + (lane & 15)) * 144 + (lane >> 4) * 16;
            b16x8 bf0 = *(const b16x8*)(Bs + colb);
            b16x8 bf1 = *(const b16x8*)(Bs + colb + 64);
            f32x4 acc = (f32x4){0.f, 0.f, 0.f, 0.f};
            acc = __builtin_amdgcn_mfma_f32_16x16x32_bf16(af0, bf0, acc, 0, 0, 0);
            acc = __builtin_amdgcn_mfma_f32_16x16x32_bf16(af1, bf1, acc, 0, 0, 0);
            const float bm = bmS[ct * 16 + (lane & 15)];
            #pragma unroll
            for (int r = 0; r < 4; r++) {
                float l = acc[r] + bm;
                float e = __expf(l);
                S[r] += e;
                Wm[r] = fmaf(e, l, Wm[r]);
            }
        }
    }
    #pragma unroll
    for (int r = 0; r < 4; r++) {
        float s = S[r], w = Wm[r];
        #pragma unroll
        for (int o = 1; o < 16; o <<= 1) {
            s += __shfl_xor(s, o, 64);
            w += __shfl_xor(w, o, 64);
        }
        if ((lane & 15) == 0) {
            int row = r0 + wid * 16 + (lane >> 4) * 4 + r;
            Spart[blockIdx.y * BT + row] = s;
            Wmpart[blockIdx.y * BT + row] = w;
        }
    }
}

// ---------------- merged tail: entropy / logp / value / actions ----------------
__global__ __launch_bounds__(256) void tail_k(const float* __restrict__ Spart,
        const float* __restrict__ Wmpart, const unsigned short* __restrict__ L2b,
        const unsigned short* __restrict__ WT3, const float* __restrict__ b3,
        const float* __restrict__ wmask, const int* __restrict__ acts,
        const float* __restrict__ cw3, const float* __restrict__ cb3,
        float* __restrict__ out)
{
    const int bid = blockIdx.x, tid = threadIdx.x;
    if (bid < 80) {
        const int rt = bid * 256 + tid;
        float s = 0.f, wm = 0.f;
        #pragma unroll
        for (int j = 0; j < 8; j++) { s += Spart[j * BT + rt]; wm += Wmpart[j * BT + rt]; }
        const float l = logf(s);
        const int t = rt >> 10, b = rt & 1023;
        out[2 * BT + b * Tlen + t] = l - wm / s;
    } else if (bid < 160) {
        const int rt = (bid - 80) * 256 + tid;
        float s = 0.f;
        #pragma unroll
        for (int j = 0; j < 8; j++) s += Spart[j * BT + rt];
        const int t = rt >> 10, b = rt & 1023;
        const int a = acts[b * Tlen + t];
        const unsigned short* ar = L2b + (size_t)rt * 128;
        const unsigned short* wr = WT3 + (size_t)a * 64;
        float dot = 0.f;
        #pragma unroll 16
        for (int k = 0; k < 64; k++) dot = fmaf(b2f(ar[k]), b2f(wr[k]), dot);
        out[BT + b * Tlen + t] = dot + b3[a] + wmask[a] - logf(s);
    } else if (bid < 240) {
        const int rt = (bid - 160) * 256 + tid;
        const unsigned short* c = L2b + (size_t)rt * 128 + 64;
        float s = cb3[0];
        #pragma unroll 16
        for (int k = 0; k < 64; k++) s = fmaf(b2f(c[k]), cw3[k], s);
        const int t = rt >> 10, b = rt & 1023;
        out[3 * BT + b * Tlen + t] = s;
    } else {
        const int rt = (bid - 240) * 256 + tid;
        out[rt] = (float)acts[rt];
    }
}

extern "C" void kernel_launch(void* const* d_in, const int* in_sizes, int n_in,
                              void* d_out, int out_size, void* d_ws, size_t ws_size,
                              hipStream_t stream)
{
    const float* img  = (const float*)d_in[0];
    const float* box  = (const float*)d_in[1];
    const int*   acts = (const int*)d_in[2];
    const float* fr_W = (const float*)d_in[3];
    const float* fr_b = (const float*)d_in[4];
    const float* b1W1 = (const float*)d_in[5];
    const float* b1b1 = (const float*)d_in[6];
    const float* b1W2 = (const float*)d_in[7];
    const float* b1b2 = (const float*)d_in[8];
    const float* b2W1 = (const float*)d_in[9];
    const float* b2b1 = (const float*)d_in[10];
    const float* b2W2 = (const float*)d_in[11];
    const float* b2b2 = (const float*)d_in[12];
    const float* lng  = (const float*)d_in[13];
    const float* lnb  = (const float*)d_in[14];
    const float* encW = (const float*)d_in[15];
    const float* encb = (const float*)d_in[16];
    const float* emb  = (const float*)d_in[17];
    const float* Wih  = (const float*)d_in[18];
    const float* bih  = (const float*)d_in[19];
    const float* Whh  = (const float*)d_in[20];
    const float* bhh  = (const float*)d_in[21];
    const float* aW1  = (const float*)d_in[22];
    const float* ab1  = (const float*)d_in[23];
    const float* aW2  = (const float*)d_in[24];
    const float* ab2  = (const float*)d_in[25];
    const float* aW3  = (const float*)d_in[26];
    const float* ab3  = (const float*)d_in[27];
    const float* cW1  = (const float*)d_in[28];
    const float* cb1  = (const float*)d_in[29];
    const float* cW2  = (const float*)d_in[30];
    const float* cb2  = (const float*)d_in[31];
    const float* cW3  = (const float*)d_in[32];
    const float* cb3  = (const float*)d_in[33];
    const float* wmask= (const float*)d_in[34];
    float* out = (float*)d_out;

    // ---- workspace ----
    char* w = (char*)d_ws;
    unsigned short* WihT  = (unsigned short*)w; w += (size_t)786432 * 2;
    unsigned short* WhhT  = (unsigned short*)w; w += (size_t)786432 * 2;
    unsigned short* frWT  = (unsigned short*)w; w += (size_t)1179648 * 2;
    unsigned short* b1W1T = (unsigned short*)w; w += (size_t)262144 * 2;
    unsigned short* b1W2T = (unsigned short*)w; w += (size_t)262144 * 2;
    unsigned short* b2W1T = (unsigned short*)w; w += (size_t)262144 * 2;
    unsigned short* b2W2T = (unsigned short*)w; w += (size_t)262144 * 2;
    unsigned short* encWT = (unsigned short*)w; w += (size_t)262144 * 2;
    unsigned short* W1cT  = (unsigned short*)w; w += (size_t)65536 * 2;
    unsigned short* W2cT  = (unsigned short*)w; w += (size_t)16384 * 2;
    unsigned short* WT3   = (unsigned short*)w; w += (size_t)640000 * 2;
    float* b1c = (float*)w;                     w += 128 * 4;
    float* b2c = (float*)w;                     w += 128 * 4;
    unsigned short* embB  = (unsigned short*)w; w += (size_t)10112 * 512 * 2;
    unsigned short* GHemb = (unsigned short*)w; w += (size_t)10112 * 1536 * 2;
    unsigned short* HALLb = (unsigned short*)w; w += (size_t)10485760 * 2;
    unsigned short* L1b   = (unsigned short*)w; w += (size_t)2621440 * 2;
    unsigned short* L2b   = (unsigned short*)w; w += (size_t)2621440 * 2;
    unsigned short* HB0   = (unsigned short*)w; w += (size_t)524288 * 2;
    float* Spart = (float*)w;                   w += (size_t)8 * BT * 4;
    float* Wmpart= (float*)w;                   w += (size_t)8 * BT * 4;
    char* arena = w;                            w += (size_t)20971520;

    unsigned short* A0 = (unsigned short*)arena;
    float* Xe  = (float*)(arena + 4718592);
    float* Ye  = Xe + 524288;
    float* T1e = Ye + 524288;
    float* T2e = T1e + 524288;

    const dim3 blk(256);

    // ---- all weight prep in one launch ----
    prep_all_k<<<12083, blk, 0, stream>>>(Wih, Whh, fr_W, b1W1, b1W2, b2W1, b2W2,
            encW, aW1, cW1, aW3, aW2, cW2, ab1, cb1, ab2, cb2, emb, img, box,
            WihT, WhhT, frWT, b1W1T, b1W2T, b2W1T, b2W2T, encWT, W1cT, W2cT,
            WT3, b1c, b2c, embB, A0);

    // ---- GHemb = embB @ Whh^T over vocab ----
    gemm_big_k<<<dim3(12, 79), blk, 0, stream>>>(embB, WhhT, GHemb, 1536, 512);

    // ---- encoder (bf16 MFMA, LN fp32) — proven r6 chain ----
    gemm_bf_k<0, 1, 0, 0><<<dim3(8, 16), blk, 0, stream>>>(A0, frWT, fr_b, Xe, nullptr, 1024, 512, 2304);
    ln_k<<<1024, blk, 0, stream>>>(Xe, nullptr, nullptr, nullptr, Ye);
    gemm_bf_k<1, 1, 0, 1><<<dim3(8, 16), blk, 0, stream>>>(Ye, b1W1T, b1b1, T1e, nullptr, 1024, 512, 512);
    gemm_bf_k<0, 1, 0, 1><<<dim3(8, 16), blk, 0, stream>>>(T1e, b1W2T, b1b2, T2e, nullptr, 1024, 512, 512);
    ln_k<<<1024, blk, 0, stream>>>(T2e, Xe, nullptr, nullptr, Ye);
    gemm_bf_k<1, 1, 0, 1><<<dim3(8, 16), blk, 0, stream>>>(Ye, b2W1T, b2b1, T1e, nullptr, 1024, 512, 512);
    gemm_bf_k<0, 1, 0, 1><<<dim3(8, 16), blk, 0, stream>>>(T1e, b2W2T, b2b2, T2e, nullptr, 1024, 512, 512);
    ln_k<<<1024, blk, 0, stream>>>(Xe, T2e, lng, lnb, Ye);
    gemm_bf_k<0, 0, 1, 1><<<dim3(8, 16), blk, 0, stream>>>(Ye, encWT, encb, nullptr, HB0, 1024, 512, 512);

    // ---- GRU scan: one fused kernel per step ----
    for (int t = 0; t < Tlen; ++t) {
        const unsigned short* Hprev = t ? HALLb + (size_t)(t - 1) * 524288 : HB0;
        gru_step3_k<<<dim3(32, 16), blk, 0, stream>>>(Hprev, WihT, bih, bhh,
                GHemb, emb, acts, t, HALLb + (size_t)t * 524288);
    }

    // ---- fused heads ----
    gemm_bf_k<2, 0, 1, 0><<<dim3(2, 320), blk, 0, stream>>>(HALLb, W1cT, b1c,
            nullptr, L1b, BT, 128, 512);
    gemm_bf_k<2, 0, 1, 0><<<dim3(2, 320), blk, 0, stream>>>(L1b, W2cT, b2c,
            nullptr, L2b, BT, 128, 128);
    logits3_k<<<dim3(320, 8), blk, 0, stream>>>(L2b, WT3, ab3, wmask, Spart, Wmpart);
    tail_k<<<320, blk, 0, stream>>>(Spart, Wmpart, L2b, WT3, ab3, wmask, acts,
            cW3, cb3, out);
}

// Round 10
// 405.202 us; speedup vs baseline: 2.8729x; 1.0443x over previous
//
#include <hip/hip_runtime.h>
#include <math.h>

#define Tlen 20
#define Vv 10000
#define BT 20480

typedef __attribute__((ext_vector_type(8))) short b16x8;
typedef __attribute__((ext_vector_type(4))) float f32x4;

__device__ __forceinline__ unsigned short f2b(float f){
    union { float f; unsigned u; } v; v.f = f;
    unsigned r = v.u + 0x7FFFu + ((v.u >> 16) & 1u);
    return (unsigned short)(r >> 16);
}
__device__ __forceinline__ float b2f(unsigned short h){
    union { unsigned u; float f; } v; v.u = ((unsigned)h) << 16;
    return v.f;
}
__device__ __forceinline__ void gload16(const void* g, void* l){
    __builtin_amdgcn_global_load_lds(
        (const __attribute__((address_space(1))) unsigned int*)g,
        (__attribute__((address_space(3))) unsigned int*)l, 16, 0, 0);
}
__device__ __forceinline__ float fast_sig(float x){ return 1.f / (1.f + __expf(-x)); }
__device__ __forceinline__ float fast_tanh(float x){ return 1.f - 2.f / (__expf(2.f * x) + 1.f); }

// ---------------- bf16 MFMA GEMM 64x64 tile, device body ----------------
// A bf16 [M,K] (or fp32 if AF32), BT [N,K] bf16. RES: add Radd fp32 in epilogue.
template<int ACT, int OUTF, int OUTB, int AF32, int RES>
__device__ __forceinline__ void gemm_bf_dev(
        const void* __restrict__ Av, const unsigned short* __restrict__ BTp,
        const float* __restrict__ bias, const float* __restrict__ Radd,
        float* __restrict__ Cf, unsigned short* __restrict__ Cb,
        int N, int K, int bx, int by)
{
    __shared__ __align__(16) char As[64 * 80];
    __shared__ __align__(16) char Bs[64 * 80];
    const int tid = threadIdx.x;
    const int wid = tid >> 6, lane = tid & 63;
    const int row0 = by * 64, col0 = bx * 64;
    const int srow = tid >> 2, sslot = tid & 3;
    f32x4 acc[4];
    #pragma unroll
    for (int i = 0; i < 4; i++) acc[i] = (f32x4){0.f, 0.f, 0.f, 0.f};
    const int afoff = (wid * 16 + (lane & 15)) * 80 + (lane >> 4) * 16;
    for (int k0 = 0; k0 < K; k0 += 32) {
        b16x8 av, bv;
        if (AF32) {
            const float* Af = (const float*)Av + (size_t)(row0 + srow) * K + k0 + sslot * 8;
            float4 a0 = *(const float4*)Af;
            float4 a1 = *(const float4*)(Af + 4);
            av[0]=(short)f2b(a0.x); av[1]=(short)f2b(a0.y); av[2]=(short)f2b(a0.z); av[3]=(short)f2b(a0.w);
            av[4]=(short)f2b(a1.x); av[5]=(short)f2b(a1.y); av[6]=(short)f2b(a1.z); av[7]=(short)f2b(a1.w);
        } else {
            av = *(const b16x8*)((const unsigned short*)Av + (size_t)(row0 + srow) * K + k0 + sslot * 8);
        }
        bv = *(const b16x8*)(BTp + (size_t)(col0 + srow) * K + k0 + sslot * 8);
        __syncthreads();
        *(b16x8*)(As + srow * 80 + sslot * 16) = av;
        *(b16x8*)(Bs + srow * 80 + sslot * 16) = bv;
        __syncthreads();
        b16x8 af = *(const b16x8*)(As + afoff);
        #pragma unroll
        for (int ct = 0; ct < 4; ct++) {
            b16x8 bf = *(const b16x8*)(Bs + (ct * 16 + (lane & 15)) * 80 + (lane >> 4) * 16);
            acc[ct] = __builtin_amdgcn_mfma_f32_16x16x32_bf16(af, bf, acc[ct], 0, 0, 0);
        }
    }
    const int orow = row0 + wid * 16 + (lane >> 4) * 4;
    #pragma unroll
    for (int ct = 0; ct < 4; ct++) {
        int col = col0 + ct * 16 + (lane & 15);
        float bb = bias ? bias[col] : 0.f;
        #pragma unroll
        for (int r = 0; r < 4; r++) {
            float v = acc[ct][r] + bb;
            if (ACT == 1) v = 0.5f * v * (1.f + erff(v * 0.70710678118654752f));
            else if (ACT == 2) v = tanhf(v);
            size_t idx = (size_t)(orow + r) * N + col;
            if (RES) v += Radd[idx];
            if (OUTF) Cf[idx] = v;
            if (OUTB) Cb[idx] = f2b(v);
        }
    }
}

template<int ACT, int OUTF, int OUTB, int AF32, int RES>
__global__ __launch_bounds__(256) void gemm_bf_k(
        const void* __restrict__ Av, const unsigned short* __restrict__ BTp,
        const float* __restrict__ bias, const float* __restrict__ Radd,
        float* __restrict__ Cf, unsigned short* __restrict__ Cb, int N, int K)
{
    gemm_bf_dev<ACT, OUTF, OUTB, AF32, RES>(Av, BTp, bias, Radd, Cf, Cb, N, K,
            blockIdx.x, blockIdx.y);
}

// ---------------- LN fused into GEMM: C = act((LN(A)[*g+b]) @ BT^T + bias) ----------------
// A fp32 [1024][512], K=512 fixed. Per-row mean/var computed in-block (rows = its 64).
template<int ACT, int AFFINE, int OUTF, int OUTB>
__global__ __launch_bounds__(256) void gemm_ln_bf_k(
        const float* __restrict__ A, const unsigned short* __restrict__ BTp,
        const float* __restrict__ bias, const float* __restrict__ g,
        const float* __restrict__ be, float* __restrict__ Cf,
        unsigned short* __restrict__ Cb)
{
    __shared__ __align__(16) char As[64 * 80];
    __shared__ __align__(16) char Bs[64 * 80];
    __shared__ float sMean[64], sInv[64];
    const int tid = threadIdx.x;
    const int wid = tid >> 6, lane = tid & 63;
    const int row0 = blockIdx.y * 64, col0 = blockIdx.x * 64;
    const int srow = tid >> 2, sslot = tid & 3;
    // ---- per-row LN stats: 4 threads/row, 128 floats each ----
    {
        const float4* Ar = (const float4*)(A + (size_t)(row0 + srow) * 512 + sslot * 128);
        float s = 0.f, s2 = 0.f;
        #pragma unroll
        for (int i = 0; i < 32; i++) {
            float4 v = Ar[i];
            s += v.x + v.y + v.z + v.w;
            s2 += v.x * v.x + v.y * v.y + v.z * v.z + v.w * v.w;
        }
        s += __shfl_xor(s, 1, 64);  s += __shfl_xor(s, 2, 64);
        s2 += __shfl_xor(s2, 1, 64); s2 += __shfl_xor(s2, 2, 64);
        if (sslot == 0) {
            float m = s * (1.f / 512.f);
            sMean[srow] = m;
            sInv[srow] = rsqrtf(s2 * (1.f / 512.f) - m * m + 1e-5f);
        }
    }
    __syncthreads();
    f32x4 acc[4];
    #pragma unroll
    for (int i = 0; i < 4; i++) acc[i] = (f32x4){0.f, 0.f, 0.f, 0.f};
    const int afoff = (wid * 16 + (lane & 15)) * 80 + (lane >> 4) * 16;
    for (int k0 = 0; k0 < 512; k0 += 32) {
        const float* Af = A + (size_t)(row0 + srow) * 512 + k0 + sslot * 8;
        float4 a0 = *(const float4*)Af;
        float4 a1 = *(const float4*)(Af + 4);
        const float m = sMean[srow], iv = sInv[srow];
        float y[8] = {(a0.x-m)*iv, (a0.y-m)*iv, (a0.z-m)*iv, (a0.w-m)*iv,
                      (a1.x-m)*iv, (a1.y-m)*iv, (a1.z-m)*iv, (a1.w-m)*iv};
        if (AFFINE) {
            const int kb = k0 + sslot * 8;
            float4 g0 = *(const float4*)(g + kb), g1 = *(const float4*)(g + kb + 4);
            float4 e0 = *(const float4*)(be + kb), e1 = *(const float4*)(be + kb + 4);
            y[0] = y[0]*g0.x + e0.x; y[1] = y[1]*g0.y + e0.y;
            y[2] = y[2]*g0.z + e0.z; y[3] = y[3]*g0.w + e0.w;
            y[4] = y[4]*g1.x + e1.x; y[5] = y[5]*g1.y + e1.y;
            y[6] = y[6]*g1.z + e1.z; y[7] = y[7]*g1.w + e1.w;
        }
        b16x8 av;
        #pragma unroll
        for (int i = 0; i < 8; i++) av[i] = (short)f2b(y[i]);
        b16x8 bv = *(const b16x8*)(BTp + (size_t)(col0 + srow) * 512 + k0 + sslot * 8);
        __syncthreads();
        *(b16x8*)(As + srow * 80 + sslot * 16) = av;
        *(b16x8*)(Bs + srow * 80 + sslot * 16) = bv;
        __syncthreads();
        b16x8 af = *(const b16x8*)(As + afoff);
        #pragma unroll
        for (int ct = 0; ct < 4; ct++) {
            b16x8 bf = *(const b16x8*)(Bs + (ct * 16 + (lane & 15)) * 80 + (lane >> 4) * 16);
            acc[ct] = __builtin_amdgcn_mfma_f32_16x16x32_bf16(af, bf, acc[ct], 0, 0, 0);
        }
    }
    const int orow = row0 + wid * 16 + (lane >> 4) * 4;
    #pragma unroll
    for (int ct = 0; ct < 4; ct++) {
        int col = col0 + ct * 16 + (lane & 15);
        float bb = bias[col];
        #pragma unroll
        for (int r = 0; r < 4; r++) {
            float v = acc[ct][r] + bb;
            if (ACT == 1) v = 0.5f * v * (1.f + erff(v * 0.70710678118654752f));
            size_t idx = (size_t)(orow + r) * 512 + col;
            if (OUTF) Cf[idx] = v;
            if (OUTB) Cb[idx] = f2b(v);
        }
    }
}

// ---------------- big MFMA GEMM device body: 128x128 tile, gload_lds, dbuf ----------------
__device__ __forceinline__ void gemm_big_dev(
        const unsigned short* __restrict__ Aptr, const unsigned short* __restrict__ Bptr,
        unsigned short* __restrict__ C, int N, int K, int idx, int nwgx, int nwg)
{
    __shared__ __align__(16) unsigned short As[2][128 * 32];
    __shared__ __align__(16) unsigned short Bs[2][128 * 32];
    const int tid = threadIdx.x, w = tid >> 6, lane = tid & 63;
    const int l15 = lane & 15, lh = lane >> 4;
    const int q = nwg >> 3, r = nwg & 7;
    const int xcd = idx & 7, pos = idx >> 3;
    const int wgid = (xcd < r ? xcd * (q + 1) : r * (q + 1) + (xcd - r) * q) + pos;
    const int bx = wgid % nwgx, by = wgid / nwgx;
    const int row0 = by * 128, col0 = bx * 128;
    const int wr = w >> 1, wc = w & 1;
    const int slw = ((lane & 3) ^ ((lane >> 2) & 3) ^ ((lane >> 4) & 3)) & 3;
    const int pa  = (lh ^ (l15 & 3) ^ ((l15 >> 2) & 3)) & 3;
    f32x4 acc[4][4];
    #pragma unroll
    for (int i = 0; i < 4; i++)
        #pragma unroll
        for (int j = 0; j < 4; j++) acc[i][j] = (f32x4){0.f, 0.f, 0.f, 0.f};
    const int nkt = K >> 5;
    #pragma unroll
    for (int c = 0; c < 2; c++) {
        int ch = w * 2 + c, rr = ch * 16 + (lane >> 2);
        gload16(Aptr + (size_t)(row0 + rr) * K + slw * 8, &As[0][ch * 512]);
        gload16(Bptr + (size_t)(col0 + rr) * K + slw * 8, &Bs[0][ch * 512]);
    }
    __syncthreads();
    for (int kt = 0; kt < nkt; kt++) {
        const int buf = kt & 1;
        if (kt + 1 < nkt) {
            const int k0 = (kt + 1) << 5;
            #pragma unroll
            for (int c = 0; c < 2; c++) {
                int ch = w * 2 + c, rr = ch * 16 + (lane >> 2);
                gload16(Aptr + (size_t)(row0 + rr) * K + k0 + slw * 8, &As[buf ^ 1][ch * 512]);
                gload16(Bptr + (size_t)(col0 + rr) * K + k0 + slw * 8, &Bs[buf ^ 1][ch * 512]);
            }
        }
        b16x8 af[4], bf[4];
        #pragma unroll
        for (int f = 0; f < 4; f++) {
            af[f] = *(const b16x8*)(&As[buf][(wr * 64 + f * 16 + l15) * 32 + pa * 8]);
            bf[f] = *(const b16x8*)(&Bs[buf][(wc * 64 + f * 16 + l15) * 32 + pa * 8]);
        }
        #pragma unroll
        for (int i = 0; i < 4; i++)
            #pragma unroll
            for (int j = 0; j < 4; j++)
                acc[i][j] = __builtin_amdgcn_mfma_f32_16x16x32_bf16(af[i], bf[j], acc[i][j], 0, 0, 0);
        __syncthreads();
    }
    #pragma unroll
    for (int i = 0; i < 4; i++) {
        const int orow = row0 + wr * 64 + i * 16 + lh * 4;
        #pragma unroll
        for (int j = 0; j < 4; j++) {
            const int col = col0 + wc * 64 + j * 16 + l15;
            #pragma unroll
            for (int rr2 = 0; rr2 < 4; rr2++)
                C[(size_t)(orow + rr2) * N + col] = f2b(acc[i][j][rr2]);
        }
    }
}

// ---------------- union launch: GHemb big-GEMM (948 blocks) + encoder fr-GEMM (128) ----------------
__global__ __launch_bounds__(256) void big_fr_k(
        const unsigned short* __restrict__ embB, const unsigned short* __restrict__ WhhT,
        unsigned short* __restrict__ GHemb,
        const unsigned short* __restrict__ A0, const unsigned short* __restrict__ frWT,
        const float* __restrict__ fr_b, float* __restrict__ Xe)
{
    const int bid = blockIdx.x;
    if (bid < 128) {
        gemm_bf_dev<0, 1, 0, 0, 0>(A0, frWT, fr_b, nullptr, Xe, nullptr,
                512, 2304, bid & 7, bid >> 3);
    } else {
        gemm_big_dev(embB, WhhT, GHemb, 1536, 512, bid - 128, 12, 948);
    }
}

// ---------------- merged weight-prep ----------------
__device__ void tileT_dev(const float* __restrict__ W, unsigned short* __restrict__ WT,
        int K, int N, int bx, int by)
{
    __shared__ float s[32][33];
    const int n0 = bx * 32, k0 = by * 32;
    const int tx = threadIdx.x & 31, ty = threadIdx.x >> 5;
    #pragma unroll
    for (int i = 0; i < 32; i += 8) {
        int k = k0 + ty + i, n = n0 + tx;
        s[ty + i][tx] = (k < K && n < N) ? W[(size_t)k * N + n] : 0.f;
    }
    __syncthreads();
    #pragma unroll
    for (int i = 0; i < 32; i += 8) {
        int n = n0 + ty + i, k = k0 + tx;
        if (n < N && k < K) WT[(size_t)n * K + k] = f2b(s[tx][ty + i]);
    }
}

__global__ __launch_bounds__(256) void prep_all_k(
        const float* __restrict__ Wih, const float* __restrict__ Whh,
        const float* __restrict__ frW, const float* __restrict__ b1W1,
        const float* __restrict__ b1W2, const float* __restrict__ b2W1,
        const float* __restrict__ b2W2, const float* __restrict__ encW,
        const float* __restrict__ aW1, const float* __restrict__ cW1,
        const float* __restrict__ aW3, const float* __restrict__ aW2,
        const float* __restrict__ cW2, const float* __restrict__ ab1,
        const float* __restrict__ cb1, const float* __restrict__ ab2,
        const float* __restrict__ cb2, const float* __restrict__ emb,
        const float* __restrict__ img, const float* __restrict__ box,
        unsigned short* __restrict__ WihT, unsigned short* __restrict__ WhhT,
        unsigned short* __restrict__ frWT, unsigned short* __restrict__ b1W1T,
        unsigned short* __restrict__ b1W2T, unsigned short* __restrict__ b2W1T,
        unsigned short* __restrict__ b2W2T, unsigned short* __restrict__ encWT,
        unsigned short* __restrict__ W1cT, unsigned short* __restrict__ W2cT,
        unsigned short* __restrict__ WT3, float* __restrict__ b1c,
        float* __restrict__ b2c, unsigned short* __restrict__ embB,
        unsigned short* __restrict__ A0)
{
    int bid = blockIdx.x;
    const int tid = threadIdx.x;
    if (bid < 768) { tileT_dev(Wih, WihT, 512, 1536, bid % 48, bid / 48); return; }
    bid -= 768;
    if (bid < 768) { tileT_dev(Whh, WhhT, 512, 1536, bid % 48, bid / 48); return; }
    bid -= 768;
    if (bid < 1152) { tileT_dev(frW, frWT, 2304, 512, bid % 16, bid / 16); return; }
    bid -= 1152;
    if (bid < 256) { tileT_dev(b1W1, b1W1T, 512, 512, bid % 16, bid / 16); return; }
    bid -= 256;
    if (bid < 256) { tileT_dev(b1W2, b1W2T, 512, 512, bid % 16, bid / 16); return; }
    bid -= 256;
    if (bid < 256) { tileT_dev(b2W1, b2W1T, 512, 512, bid % 16, bid / 16); return; }
    bid -= 256;
    if (bid < 256) { tileT_dev(b2W2, b2W2T, 512, 512, bid % 16, bid / 16); return; }
    bid -= 256;
    if (bid < 256) { tileT_dev(encW, encWT, 512, 512, bid % 16, bid / 16); return; }
    bid -= 256;
    if (bid < 32) { tileT_dev(aW1, W1cT, 512, 64, bid % 2, bid / 2); return; }
    bid -= 32;
    if (bid < 32) { tileT_dev(cW1, W1cT + (size_t)64 * 512, 512, 64, bid % 2, bid / 2); return; }
    bid -= 32;
    if (bid < 626) { tileT_dev(aW3, WT3, 64, 10000, bid % 313, bid / 313); return; }
    bid -= 626;
    if (bid < 64) {
        int idx = bid * 256 + tid;
        int j = idx >> 7, k = idx & 127;
        float v = 0.f;
        if (j < 64 && k < 64) v = aW2[(size_t)k * 64 + j];
        else if (j >= 64 && k >= 64) v = cW2[(size_t)(k - 64) * 64 + (j - 64)];
        W2cT[idx] = f2b(v);
        return;
    }
    bid -= 64;
    if (bid < 1) {
        if (tid < 128) b1c[tid] = (tid < 64) ? ab1[tid] : cb1[tid - 64];
        else { int i = tid - 128; b2c[i] = (i < 64) ? ab2[i] : cb2[i - 64]; }
        return;
    }
    bid -= 1;
    if (bid < 5056) {
        int idx = bid * 256 + tid;
        int row = idx >> 7, c4 = (idx & 127) * 4;
        float4 v = {0.f, 0.f, 0.f, 0.f};
        if (row < Vv) v = *(const float4*)(emb + (size_t)row * 512 + c4);
        ushort4 o; o.x = f2b(v.x); o.y = f2b(v.y); o.z = f2b(v.z); o.w = f2b(v.w);
        *(ushort4*)(embB + (size_t)row * 512 + c4) = o;
        return;
    }
    bid -= 5056;
    {
        int idx = bid * 256 + tid;
        int row = idx / 576, c4 = (idx - row * 576) * 4;
        float4 v = (c4 < 2048) ? *(const float4*)(img + (size_t)row * 2048 + c4)
                               : *(const float4*)(box + (size_t)row * 256 + (c4 - 2048));
        ushort4 o; o.x = f2b(v.x); o.y = f2b(v.y); o.z = f2b(v.z); o.w = f2b(v.w);
        *(ushort4*)(A0 + (size_t)row * 2304 + c4) = o;
    }
}

// ---------------- one GRU step (r6-proven): A preloaded, B via gload_lds ----------------
__global__ __launch_bounds__(256) void gru_step3_k(
        const unsigned short* __restrict__ Hprev,
        const unsigned short* __restrict__ WihT,
        const float* __restrict__ bih, const float* __restrict__ bhh,
        const unsigned short* __restrict__ GHemb,
        const float* __restrict__ emb, const int* __restrict__ acts, int t,
        unsigned short* __restrict__ Hout)
{
    __shared__ __align__(16) unsigned short sB[48 * 512];
    const int tid = threadIdx.x, w = tid >> 6, lane = tid & 63;
    const int l15 = lane & 15, lh = lane >> 4;
    const int d0 = blockIdx.x * 16;
    const int rows0 = blockIdx.y * 64 + w * 16;
    const unsigned short* Arow = Hprev + (size_t)(rows0 + l15) * 512 + lh * 8;
    b16x8 a[16];
    #pragma unroll
    for (int kk = 0; kk < 16; kk++) a[kk] = *(const b16x8*)(Arow + kk * 32);
    #pragma unroll
    for (int c = 0; c < 12; c++) {
        const int ch = w * 12 + c;
        const int g = ch >> 4, col = ch & 15;
        const int sl = lane ^ (ch & 7);
        gload16(WihT + (size_t)(g * 512 + d0 + col) * 512 + sl * 8, &sB[ch * 512]);
    }
    __syncthreads();
    f32x4 ar = (f32x4){0.f,0.f,0.f,0.f}, az = ar, an = ar;
    #pragma unroll
    for (int kk = 0; kk < 16; kk++) {
        const int sl = ((kk * 4 + lh) ^ (l15 & 7));
        b16x8 b0 = *(const b16x8*)(&sB[(l15) * 512 + sl * 8]);
        b16x8 b1 = *(const b16x8*)(&sB[(16 + l15) * 512 + sl * 8]);
        b16x8 b2 = *(const b16x8*)(&sB[(32 + l15) * 512 + sl * 8]);
        ar = __builtin_amdgcn_mfma_f32_16x16x32_bf16(a[kk], b0, ar, 0, 0, 0);
        az = __builtin_amdgcn_mfma_f32_16x16x32_bf16(a[kk], b1, az, 0, 0, 0);
        an = __builtin_amdgcn_mfma_f32_16x16x32_bf16(a[kk], b2, an, 0, 0, 0);
    }
    const int d = d0 + l15;
    const float bi0 = bih[d], bi1 = bih[512 + d], bi2 = bih[1024 + d];
    const float bh0 = bhh[d], bh1 = bhh[512 + d], bh2 = bhh[1024 + d];
    #pragma unroll
    for (int reg = 0; reg < 4; reg++) {
        const int row = rows0 + lh * 4 + reg;
        float hr = bh0, hz = bh1, hn = bh2, ix = 0.f;
        if (t) {
            const int ap = acts[row * Tlen + t - 1];
            const size_t gb = (size_t)ap * 1536;
            hr += b2f(GHemb[gb + d]);
            hz += b2f(GHemb[gb + 512 + d]);
            hn += b2f(GHemb[gb + 1024 + d]);
            ix = emb[(size_t)ap * 512 + d];
        }
        const float rr = fast_sig(ar[reg] + bi0 + hr);
        const float zz = fast_sig(az[reg] + bi1 + hz);
        const float nn = fast_tanh(an[reg] + bi2 + rr * hn);
        Hout[(size_t)row * 512 + d] = f2b((1.f - zz) * nn + zz * ix);
    }
}

// ---------------- fused heads: L2b = tanh(tanh(H @ W1c + b1c) @ W2c + b2c) ----------------
// 320 blocks x 64 rows. Phase 1 per-wave (16 rows, all 128 cols) from global frags;
// Ts per-wave in LDS (no barrier); phase 2 K=128.
__global__ __launch_bounds__(256) void heads_k(
        const unsigned short* __restrict__ H, const unsigned short* __restrict__ W1cT,
        const float* __restrict__ b1c, const unsigned short* __restrict__ W2cT,
        const float* __restrict__ b2c, unsigned short* __restrict__ L2b)
{
    __shared__ __align__(16) unsigned short Ts[64 * 136];
    const int tid = threadIdx.x, w = tid >> 6, lane = tid & 63;
    const int l15 = lane & 15, lh = lane >> 4;
    const int r0 = blockIdx.x * 64;
    const unsigned short* Arow = H + (size_t)(r0 + w * 16 + l15) * 512 + lh * 8;
    f32x4 acc[8];
    #pragma unroll
    for (int i = 0; i < 8; i++) acc[i] = (f32x4){0.f, 0.f, 0.f, 0.f};
    for (int kt = 0; kt < 16; kt++) {
        b16x8 a = *(const b16x8*)(Arow + kt * 32);
        #pragma unroll
        for (int ct = 0; ct < 8; ct++) {
            b16x8 b = *(const b16x8*)(W1cT + (size_t)(ct * 16 + l15) * 512 + kt * 32 + lh * 8);
            acc[ct] = __builtin_amdgcn_mfma_f32_16x16x32_bf16(a, b, acc[ct], 0, 0, 0);
        }
    }
    #pragma unroll
    for (int ct = 0; ct < 8; ct++) {
        const int col = ct * 16 + l15;
        const float bb = b1c[col];
        #pragma unroll
        for (int r = 0; r < 4; r++)
            Ts[(w * 16 + lh * 4 + r) * 136 + col] = f2b(tanhf(acc[ct][r] + bb));
    }
    // same-wave LDS RAW: compiler inserts lgkmcnt wait
    f32x4 acc2[8];
    #pragma unroll
    for (int i = 0; i < 8; i++) acc2[i] = (f32x4){0.f, 0.f, 0.f, 0.f};
    const unsigned short* Trow = Ts + (size_t)(w * 16 + l15) * 136 + lh * 8;
    #pragma unroll
    for (int kt = 0; kt < 4; kt++) {
        b16x8 a2 = *(const b16x8*)(Trow + kt * 32);
        #pragma unroll
        for (int ct = 0; ct < 8; ct++) {
            b16x8 b = *(const b16x8*)(W2cT + (size_t)(ct * 16 + l15) * 128 + kt * 32 + lh * 8);
            acc2[ct] = __builtin_amdgcn_mfma_f32_16x16x32_bf16(a2, b, acc2[ct], 0, 0, 0);
        }
    }
    #pragma unroll
    for (int ct = 0; ct < 8; ct++) {
        const int col = ct * 16 + l15;
        const float bb = b2c[col];
        #pragma unroll
        for (int r = 0; r < 4; r++)
            L2b[(size_t)(r0 + w * 16 + lh * 4 + r) * 128 + col] = f2b(tanhf(acc2[ct][r] + bb));
    }
}

// ---------------- logits: V-split MFMA + partial exp-sums ----------------
__global__ __launch_bounds__(256) void logits3_k(const unsigned short* __restrict__ A2b,
        const unsigned short* __restrict__ WT3, const float* __restrict__ b3,
        const float* __restrict__ wmask, float* __restrict__ Spart,
        float* __restrict__ Wmpart)
{
    __shared__ __align__(16) char Bs[64 * 144];
    __shared__ float bmS[64];
    const int tid = threadIdx.x, wid = tid >> 6, lane = tid & 63;
    const int r0 = blockIdx.x * 64;
    const int c0 = blockIdx.y * 640;
    const int cend = (c0 + 640 < 5056) ? c0 + 640 : 5056;
    const size_t abase = (size_t)(r0 + wid * 16 + (lane & 15)) * 128 + (lane >> 4) * 8;
    const b16x8 af0 = *(const b16x8*)(A2b + abase);
    const b16x8 af1 = *(const b16x8*)(A2b + abase + 32);
    float S[4] = {0.f, 0.f, 0.f, 0.f}, Wm[4] = {0.f, 0.f, 0.f, 0.f};
    for (int cc = c0; cc < cend; cc += 64) {
        __syncthreads();
        #pragma unroll
        for (int i = 0; i < 2; i++) {
            int e = tid + i * 256;
            int rr = e >> 3, slot = e & 7;
            b16x8 wv = *(const b16x8*)(WT3 + (size_t)(cc + rr) * 64 + slot * 8);
            *(b16x8*)(Bs + rr * 144 + slot * 16) = wv;
        }
        if (tid < 64) bmS[tid] = b3[cc + tid] + wmask[cc + tid];
        __syncthreads();
        #pragma unroll
        for (int ct = 0; ct < 4; ct++) {
            const int colb = (ct * 16 + (lane & 15)) * 144 + (lane >> 4) * 16;
            b16x8 bf0 = *(const b16x8*)(Bs + colb);
            b16x8 bf1 = *(const b16x8*)(Bs + colb + 64);
            f32x4 acc = (f32x4){0.f, 0.f, 0.f, 0.f};
            acc = __builtin_amdgcn_mfma_f32_16x16x32_bf16(af0, bf0, acc, 0, 0, 0);
            acc = __builtin_amdgcn_mfma_f32_16x16x32_bf16(af1, bf1, acc, 0, 0, 0);
            const float bm = bmS[ct * 16 + (lane & 15)];
            #pragma unroll
            for (int r = 0; r < 4; r++) {
                float l = acc[r] + bm;
                float e = __expf(l);
                S[r] += e;
                Wm[r] = fmaf(e, l, Wm[r]);
            }
        }
    }
    #pragma unroll
    for (int r = 0; r < 4; r++) {
        float s = S[r], w = Wm[r];
        #pragma unroll
        for (int o = 1; o < 16; o <<= 1) {
            s += __shfl_xor(s, o, 64);
            w += __shfl_xor(w, o, 64);
        }
        if ((lane & 15) == 0) {
            int row = r0 + wid * 16 + (lane >> 4) * 4 + r;
            Spart[blockIdx.y * BT + row] = s;
            Wmpart[blockIdx.y * BT + row] = w;
        }
    }
}

// ---------------- merged tail: entropy / logp / value / actions ----------------
__global__ __launch_bounds__(256) void tail_k(const float* __restrict__ Spart,
        const float* __restrict__ Wmpart, const unsigned short* __restrict__ L2b,
        const unsigned short* __restrict__ WT3, const float* __restrict__ b3,
        const float* __restrict__ wmask, const int* __restrict__ acts,
        const float* __restrict__ cw3, const float* __restrict__ cb3,
        float* __restrict__ out)
{
    const int bid = blockIdx.x, tid = threadIdx.x;
    if (bid < 80) {
        const int rt = bid * 256 + tid;
        float s = 0.f, wm = 0.f;
        #pragma unroll
        for (int j = 0; j < 8; j++) { s += Spart[j * BT + rt]; wm += Wmpart[j * BT + rt]; }
        const float l = logf(s);
        const int t = rt >> 10, b = rt & 1023;
        out[2 * BT + b * Tlen + t] = l - wm / s;
    } else if (bid < 160) {
        const int rt = (bid - 80) * 256 + tid;
        float s = 0.f;
        #pragma unroll
        for (int j = 0; j < 8; j++) s += Spart[j * BT + rt];
        const int t = rt >> 10, b = rt & 1023;
        const int a = acts[b * Tlen + t];
        const unsigned short* ar = L2b + (size_t)rt * 128;
        const unsigned short* wr = WT3 + (size_t)a * 64;
        float dot = 0.f;
        #pragma unroll 16
        for (int k = 0; k < 64; k++) dot = fmaf(b2f(ar[k]), b2f(wr[k]), dot);
        out[BT + b * Tlen + t] = dot + b3[a] + wmask[a] - logf(s);
    } else if (bid < 240) {
        const int rt = (bid - 160) * 256 + tid;
        const unsigned short* c = L2b + (size_t)rt * 128 + 64;
        float s = cb3[0];
        #pragma unroll 16
        for (int k = 0; k < 64; k++) s = fmaf(b2f(c[k]), cw3[k], s);
        const int t = rt >> 10, b = rt & 1023;
        out[3 * BT + b * Tlen + t] = s;
    } else {
        const int rt = (bid - 240) * 256 + tid;
        out[rt] = (float)acts[rt];
    }
}

extern "C" void kernel_launch(void* const* d_in, const int* in_sizes, int n_in,
                              void* d_out, int out_size, void* d_ws, size_t ws_size,
                              hipStream_t stream)
{
    const float* img  = (const float*)d_in[0];
    const float* box  = (const float*)d_in[1];
    const int*   acts = (const int*)d_in[2];
    const float* fr_W = (const float*)d_in[3];
    const float* fr_b = (const float*)d_in[4];
    const float* b1W1 = (const float*)d_in[5];
    const float* b1b1 = (const float*)d_in[6];
    const float* b1W2 = (const float*)d_in[7];
    const float* b1b2 = (const float*)d_in[8];
    const float* b2W1 = (const float*)d_in[9];
    const float* b2b1 = (const float*)d_in[10];
    const float* b2W2 = (const float*)d_in[11];
    const float* b2b2 = (const float*)d_in[12];
    const float* lng  = (const float*)d_in[13];
    const float* lnb  = (const float*)d_in[14];
    const float* encW = (const float*)d_in[15];
    const float* encb = (const float*)d_in[16];
    const float* emb  = (const float*)d_in[17];
    const float* Wih  = (const float*)d_in[18];
    const float* bih  = (const float*)d_in[19];
    const float* Whh  = (const float*)d_in[20];
    const float* bhh  = (const float*)d_in[21];
    const float* aW1  = (const float*)d_in[22];
    const float* ab1  = (const float*)d_in[23];
    const float* aW2  = (const float*)d_in[24];
    const float* ab2  = (const float*)d_in[25];
    const float* aW3  = (const float*)d_in[26];
    const float* ab3  = (const float*)d_in[27];
    const float* cW1  = (const float*)d_in[28];
    const float* cb1  = (const float*)d_in[29];
    const float* cW2  = (const float*)d_in[30];
    const float* cb2  = (const float*)d_in[31];
    const float* cW3  = (const float*)d_in[32];
    const float* cb3  = (const float*)d_in[33];
    const float* wmask= (const float*)d_in[34];
    float* out = (float*)d_out;

    // ---- workspace ----
    char* w = (char*)d_ws;
    unsigned short* WihT  = (unsigned short*)w; w += (size_t)786432 * 2;
    unsigned short* WhhT  = (unsigned short*)w; w += (size_t)786432 * 2;
    unsigned short* frWT  = (unsigned short*)w; w += (size_t)1179648 * 2;
    unsigned short* b1W1T = (unsigned short*)w; w += (size_t)262144 * 2;
    unsigned short* b1W2T = (unsigned short*)w; w += (size_t)262144 * 2;
    unsigned short* b2W1T = (unsigned short*)w; w += (size_t)262144 * 2;
    unsigned short* b2W2T = (unsigned short*)w; w += (size_t)262144 * 2;
    unsigned short* encWT = (unsigned short*)w; w += (size_t)262144 * 2;
    unsigned short* W1cT  = (unsigned short*)w; w += (size_t)65536 * 2;
    unsigned short* W2cT  = (unsigned short*)w; w += (size_t)16384 * 2;
    unsigned short* WT3   = (unsigned short*)w; w += (size_t)640000 * 2;
    float* b1c = (float*)w;                     w += 128 * 4;
    float* b2c = (float*)w;                     w += 128 * 4;
    unsigned short* embB  = (unsigned short*)w; w += (size_t)10112 * 512 * 2;
    unsigned short* GHemb = (unsigned short*)w; w += (size_t)10112 * 1536 * 2;
    unsigned short* HALLb = (unsigned short*)w; w += (size_t)10485760 * 2;
    unsigned short* L2b   = (unsigned short*)w; w += (size_t)2621440 * 2;
    unsigned short* HB0   = (unsigned short*)w; w += (size_t)524288 * 2;
    float* Spart = (float*)w;                   w += (size_t)8 * BT * 4;
    float* Wmpart= (float*)w;                   w += (size_t)8 * BT * 4;
    unsigned short* A0 = (unsigned short*)w;    w += (size_t)2359296 * 2;
    float* Xe  = (float*)w;                     w += (size_t)524288 * 4;
    float* T2  = (float*)w;                     w += (size_t)524288 * 4;
    float* Sf  = (float*)w;                     w += (size_t)524288 * 4;
    unsigned short* T1b = (unsigned short*)w;   w += (size_t)524288 * 2;
    unsigned short* T3b = (unsigned short*)w;   w += (size_t)524288 * 2;

    const dim3 blk(256);

    // 1. all weight prep
    prep_all_k<<<12083, blk, 0, stream>>>(Wih, Whh, fr_W, b1W1, b1W2, b2W1, b2W2,
            encW, aW1, cW1, aW3, aW2, cW2, ab1, cb1, ab2, cb2, emb, img, box,
            WihT, WhhT, frWT, b1W1T, b1W2T, b2W1T, b2W2T, encWT, W1cT, W2cT,
            WT3, b1c, b2c, embB, A0);

    // 2. union: GHemb big-GEMM ∥ encoder fr-GEMM
    big_fr_k<<<1076, blk, 0, stream>>>(embB, WhhT, GHemb, A0, frWT, fr_b, Xe);

    // 3-7. encoder (LN fused into consumers, residuals in producers)
    gemm_ln_bf_k<1, 0, 0, 1><<<dim3(8, 16), blk, 0, stream>>>(Xe, b1W1T, b1b1,
            nullptr, nullptr, nullptr, T1b);
    gemm_bf_k<0, 1, 0, 0, 1><<<dim3(8, 16), blk, 0, stream>>>(T1b, b1W2T, b1b2,
            Xe, T2, nullptr, 512, 512);
    gemm_ln_bf_k<1, 0, 0, 1><<<dim3(8, 16), blk, 0, stream>>>(T2, b2W1T, b2b1,
            nullptr, nullptr, nullptr, T3b);
    gemm_bf_k<0, 1, 0, 0, 1><<<dim3(8, 16), blk, 0, stream>>>(T3b, b2W2T, b2b2,
            Xe, Sf, nullptr, 512, 512);
    gemm_ln_bf_k<0, 1, 0, 1><<<dim3(8, 16), blk, 0, stream>>>(Sf, encWT, encb,
            lng, lnb, nullptr, HB0);

    // 8-27. GRU scan
    for (int t = 0; t < Tlen; ++t) {
        const unsigned short* Hprev = t ? HALLb + (size_t)(t - 1) * 524288 : HB0;
        gru_step3_k<<<dim3(32, 16), blk, 0, stream>>>(Hprev, WihT, bih, bhh,
                GHemb, emb, acts, t, HALLb + (size_t)t * 524288);
    }

    // 28-30. heads + logits + tail
    heads_k<<<320, blk, 0, stream>>>(HALLb, W1cT, b1c, W2cT, b2c, L2b);
    logits3_k<<<dim3(320, 8), blk, 0, stream>>>(L2b, WT3, ab3, wmask, Spart, Wmpart);
    tail_k<<<320, blk, 0, stream>>>(Spart, Wmpart, L2b, WT3, ab3, wmask, acts,
            cW3, cb3, out);
}

// Round 11
// 380.548 us; speedup vs baseline: 3.0590x; 1.0648x over previous
//
#include <hip/hip_runtime.h>
#include <math.h>

#define Tlen 20
#define Vv 10000
#define BT 20480

typedef __attribute__((ext_vector_type(8))) short b16x8;
typedef __attribute__((ext_vector_type(4))) float f32x4;

__device__ __forceinline__ unsigned short f2b(float f){
    union { float f; unsigned u; } v; v.f = f;
    unsigned r = v.u + 0x7FFFu + ((v.u >> 16) & 1u);
    return (unsigned short)(r >> 16);
}
__device__ __forceinline__ float b2f(unsigned short h){
    union { unsigned u; float f; } v; v.u = ((unsigned)h) << 16;
    return v.f;
}
__device__ __forceinline__ void gload16(const void* g, void* l){
    __builtin_amdgcn_global_load_lds(
        (const __attribute__((address_space(1))) unsigned int*)g,
        (__attribute__((address_space(3))) unsigned int*)l, 16, 0, 0);
}
__device__ __forceinline__ float fast_sig(float x){ return 1.f / (1.f + __expf(-x)); }
__device__ __forceinline__ float fast_tanh(float x){ return 1.f - 2.f / (__expf(2.f * x) + 1.f); }

// ---------------- bf16 MFMA GEMM 64x64 tile, device body ----------------
template<int ACT, int OUTF, int OUTB, int AF32, int RES>
__device__ __forceinline__ void gemm_bf_dev(
        const void* __restrict__ Av, const unsigned short* __restrict__ BTp,
        const float* __restrict__ bias, const float* __restrict__ Radd,
        float* __restrict__ Cf, unsigned short* __restrict__ Cb,
        int N, int K, int bx, int by)
{
    __shared__ __align__(16) char As[64 * 80];
    __shared__ __align__(16) char Bs[64 * 80];
    const int tid = threadIdx.x;
    const int wid = tid >> 6, lane = tid & 63;
    const int row0 = by * 64, col0 = bx * 64;
    const int srow = tid >> 2, sslot = tid & 3;
    f32x4 acc[4];
    #pragma unroll
    for (int i = 0; i < 4; i++) acc[i] = (f32x4){0.f, 0.f, 0.f, 0.f};
    const int afoff = (wid * 16 + (lane & 15)) * 80 + (lane >> 4) * 16;
    for (int k0 = 0; k0 < K; k0 += 32) {
        b16x8 av, bv;
        if (AF32) {
            const float* Af = (const float*)Av + (size_t)(row0 + srow) * K + k0 + sslot * 8;
            float4 a0 = *(const float4*)Af;
            float4 a1 = *(const float4*)(Af + 4);
            av[0]=(short)f2b(a0.x); av[1]=(short)f2b(a0.y); av[2]=(short)f2b(a0.z); av[3]=(short)f2b(a0.w);
            av[4]=(short)f2b(a1.x); av[5]=(short)f2b(a1.y); av[6]=(short)f2b(a1.z); av[7]=(short)f2b(a1.w);
        } else {
            av = *(const b16x8*)((const unsigned short*)Av + (size_t)(row0 + srow) * K + k0 + sslot * 8);
        }
        bv = *(const b16x8*)(BTp + (size_t)(col0 + srow) * K + k0 + sslot * 8);
        __syncthreads();
        *(b16x8*)(As + srow * 80 + sslot * 16) = av;
        *(b16x8*)(Bs + srow * 80 + sslot * 16) = bv;
        __syncthreads();
        b16x8 af = *(const b16x8*)(As + afoff);
        #pragma unroll
        for (int ct = 0; ct < 4; ct++) {
            b16x8 bf = *(const b16x8*)(Bs + (ct * 16 + (lane & 15)) * 80 + (lane >> 4) * 16);
            acc[ct] = __builtin_amdgcn_mfma_f32_16x16x32_bf16(af, bf, acc[ct], 0, 0, 0);
        }
    }
    const int orow = row0 + wid * 16 + (lane >> 4) * 4;
    #pragma unroll
    for (int ct = 0; ct < 4; ct++) {
        int col = col0 + ct * 16 + (lane & 15);
        float bb = bias ? bias[col] : 0.f;
        #pragma unroll
        for (int r = 0; r < 4; r++) {
            float v = acc[ct][r] + bb;
            if (ACT == 1) v = 0.5f * v * (1.f + erff(v * 0.70710678118654752f));
            else if (ACT == 2) v = tanhf(v);
            size_t idx = (size_t)(orow + r) * N + col;
            if (RES) v += Radd[idx];
            if (OUTF) Cf[idx] = v;
            if (OUTB) Cb[idx] = f2b(v);
        }
    }
}

template<int ACT, int OUTF, int OUTB, int AF32, int RES>
__global__ __launch_bounds__(256) void gemm_bf_k(
        const void* __restrict__ Av, const unsigned short* __restrict__ BTp,
        const float* __restrict__ bias, const float* __restrict__ Radd,
        float* __restrict__ Cf, unsigned short* __restrict__ Cb, int N, int K)
{
    gemm_bf_dev<ACT, OUTF, OUTB, AF32, RES>(Av, BTp, bias, Radd, Cf, Cb, N, K,
            blockIdx.x, blockIdx.y);
}

// ---------------- LN fused into GEMM: C = act((LN(A)[*g+b]) @ BT^T + bias) ----------------
template<int ACT, int AFFINE, int OUTF, int OUTB>
__global__ __launch_bounds__(256) void gemm_ln_bf_k(
        const float* __restrict__ A, const unsigned short* __restrict__ BTp,
        const float* __restrict__ bias, const float* __restrict__ g,
        const float* __restrict__ be, float* __restrict__ Cf,
        unsigned short* __restrict__ Cb)
{
    __shared__ __align__(16) char As[64 * 80];
    __shared__ __align__(16) char Bs[64 * 80];
    __shared__ float sMean[64], sInv[64];
    const int tid = threadIdx.x;
    const int wid = tid >> 6, lane = tid & 63;
    const int row0 = blockIdx.y * 64, col0 = blockIdx.x * 64;
    const int srow = tid >> 2, sslot = tid & 3;
    {
        const float4* Ar = (const float4*)(A + (size_t)(row0 + srow) * 512 + sslot * 128);
        float s = 0.f, s2 = 0.f;
        #pragma unroll
        for (int i = 0; i < 32; i++) {
            float4 v = Ar[i];
            s += v.x + v.y + v.z + v.w;
            s2 += v.x * v.x + v.y * v.y + v.z * v.z + v.w * v.w;
        }
        s += __shfl_xor(s, 1, 64);  s += __shfl_xor(s, 2, 64);
        s2 += __shfl_xor(s2, 1, 64); s2 += __shfl_xor(s2, 2, 64);
        if (sslot == 0) {
            float m = s * (1.f / 512.f);
            sMean[srow] = m;
            sInv[srow] = rsqrtf(s2 * (1.f / 512.f) - m * m + 1e-5f);
        }
    }
    __syncthreads();
    f32x4 acc[4];
    #pragma unroll
    for (int i = 0; i < 4; i++) acc[i] = (f32x4){0.f, 0.f, 0.f, 0.f};
    const int afoff = (wid * 16 + (lane & 15)) * 80 + (lane >> 4) * 16;
    for (int k0 = 0; k0 < 512; k0 += 32) {
        const float* Af = A + (size_t)(row0 + srow) * 512 + k0 + sslot * 8;
        float4 a0 = *(const float4*)Af;
        float4 a1 = *(const float4*)(Af + 4);
        const float m = sMean[srow], iv = sInv[srow];
        float y[8] = {(a0.x-m)*iv, (a0.y-m)*iv, (a0.z-m)*iv, (a0.w-m)*iv,
                      (a1.x-m)*iv, (a1.y-m)*iv, (a1.z-m)*iv, (a1.w-m)*iv};
        if (AFFINE) {
            const int kb = k0 + sslot * 8;
            float4 g0 = *(const float4*)(g + kb), g1 = *(const float4*)(g + kb + 4);
            float4 e0 = *(const float4*)(be + kb), e1 = *(const float4*)(be + kb + 4);
            y[0] = y[0]*g0.x + e0.x; y[1] = y[1]*g0.y + e0.y;
            y[2] = y[2]*g0.z + e0.z; y[3] = y[3]*g0.w + e0.w;
            y[4] = y[4]*g1.x + e1.x; y[5] = y[5]*g1.y + e1.y;
            y[6] = y[6]*g1.z + e1.z; y[7] = y[7]*g1.w + e1.w;
        }
        b16x8 av;
        #pragma unroll
        for (int i = 0; i < 8; i++) av[i] = (short)f2b(y[i]);
        b16x8 bv = *(const b16x8*)(BTp + (size_t)(col0 + srow) * 512 + k0 + sslot * 8);
        __syncthreads();
        *(b16x8*)(As + srow * 80 + sslot * 16) = av;
        *(b16x8*)(Bs + srow * 80 + sslot * 16) = bv;
        __syncthreads();
        b16x8 af = *(const b16x8*)(As + afoff);
        #pragma unroll
        for (int ct = 0; ct < 4; ct++) {
            b16x8 bf = *(const b16x8*)(Bs + (ct * 16 + (lane & 15)) * 80 + (lane >> 4) * 16);
            acc[ct] = __builtin_amdgcn_mfma_f32_16x16x32_bf16(af, bf, acc[ct], 0, 0, 0);
        }
    }
    const int orow = row0 + wid * 16 + (lane >> 4) * 4;
    #pragma unroll
    for (int ct = 0; ct < 4; ct++) {
        int col = col0 + ct * 16 + (lane & 15);
        float bb = bias[col];
        #pragma unroll
        for (int r = 0; r < 4; r++) {
            float v = acc[ct][r] + bb;
            if (ACT == 1) v = 0.5f * v * (1.f + erff(v * 0.70710678118654752f));
            size_t idx = (size_t)(orow + r) * 512 + col;
            if (OUTF) Cf[idx] = v;
            if (OUTB) Cb[idx] = f2b(v);
        }
    }
}

// ---------------- big MFMA GEMM device body: 128x128 tile, gload_lds, dbuf ----------------
__device__ __forceinline__ void gemm_big_dev(
        const unsigned short* __restrict__ Aptr, const unsigned short* __restrict__ Bptr,
        unsigned short* __restrict__ C, int N, int K, int idx, int nwgx, int nwg)
{
    __shared__ __align__(16) unsigned short As[2][128 * 32];
    __shared__ __align__(16) unsigned short Bs[2][128 * 32];
    const int tid = threadIdx.x, w = tid >> 6, lane = tid & 63;
    const int l15 = lane & 15, lh = lane >> 4;
    const int q = nwg >> 3, r = nwg & 7;
    const int xcd = idx & 7, pos = idx >> 3;
    const int wgid = (xcd < r ? xcd * (q + 1) : r * (q + 1) + (xcd - r) * q) + pos;
    const int bx = wgid % nwgx, by = wgid / nwgx;
    const int row0 = by * 128, col0 = bx * 128;
    const int wr = w >> 1, wc = w & 1;
    const int slw = ((lane & 3) ^ ((lane >> 2) & 3) ^ ((lane >> 4) & 3)) & 3;
    const int pa  = (lh ^ (l15 & 3) ^ ((l15 >> 2) & 3)) & 3;
    f32x4 acc[4][4];
    #pragma unroll
    for (int i = 0; i < 4; i++)
        #pragma unroll
        for (int j = 0; j < 4; j++) acc[i][j] = (f32x4){0.f, 0.f, 0.f, 0.f};
    const int nkt = K >> 5;
    #pragma unroll
    for (int c = 0; c < 2; c++) {
        int ch = w * 2 + c, rr = ch * 16 + (lane >> 2);
        gload16(Aptr + (size_t)(row0 + rr) * K + slw * 8, &As[0][ch * 512]);
        gload16(Bptr + (size_t)(col0 + rr) * K + slw * 8, &Bs[0][ch * 512]);
    }
    __syncthreads();
    for (int kt = 0; kt < nkt; kt++) {
        const int buf = kt & 1;
        if (kt + 1 < nkt) {
            const int k0 = (kt + 1) << 5;
            #pragma unroll
            for (int c = 0; c < 2; c++) {
                int ch = w * 2 + c, rr = ch * 16 + (lane >> 2);
                gload16(Aptr + (size_t)(row0 + rr) * K + k0 + slw * 8, &As[buf ^ 1][ch * 512]);
                gload16(Bptr + (size_t)(col0 + rr) * K + k0 + slw * 8, &Bs[buf ^ 1][ch * 512]);
            }
        }
        b16x8 af[4], bf[4];
        #pragma unroll
        for (int f = 0; f < 4; f++) {
            af[f] = *(const b16x8*)(&As[buf][(wr * 64 + f * 16 + l15) * 32 + pa * 8]);
            bf[f] = *(const b16x8*)(&Bs[buf][(wc * 64 + f * 16 + l15) * 32 + pa * 8]);
        }
        #pragma unroll
        for (int i = 0; i < 4; i++)
            #pragma unroll
            for (int j = 0; j < 4; j++)
                acc[i][j] = __builtin_amdgcn_mfma_f32_16x16x32_bf16(af[i], bf[j], acc[i][j], 0, 0, 0);
        __syncthreads();
    }
    #pragma unroll
    for (int i = 0; i < 4; i++) {
        const int orow = row0 + wr * 64 + i * 16 + lh * 4;
        #pragma unroll
        for (int j = 0; j < 4; j++) {
            const int col = col0 + wc * 64 + j * 16 + l15;
            #pragma unroll
            for (int rr2 = 0; rr2 < 4; rr2++)
                C[(size_t)(orow + rr2) * N + col] = f2b(acc[i][j][rr2]);
        }
    }
}

// ---------------- union launch: GHemb big-GEMM (948 blocks) + encoder fr-GEMM (128) ----------------
__global__ __launch_bounds__(256) void big_fr_k(
        const unsigned short* __restrict__ embB, const unsigned short* __restrict__ WhhT,
        unsigned short* __restrict__ GHemb,
        const unsigned short* __restrict__ A0, const unsigned short* __restrict__ frWT,
        const float* __restrict__ fr_b, float* __restrict__ Xe)
{
    const int bid = blockIdx.x;
    if (bid < 128) {
        gemm_bf_dev<0, 1, 0, 0, 0>(A0, frWT, fr_b, nullptr, Xe, nullptr,
                512, 2304, bid & 7, bid >> 3);
    } else {
        gemm_big_dev(embB, WhhT, GHemb, 1536, 512, bid - 128, 12, 948);
    }
}

// ---------------- merged weight-prep ----------------
__device__ void tileT_dev(const float* __restrict__ W, unsigned short* __restrict__ WT,
        int K, int N, int bx, int by)
{
    __shared__ float s[32][33];
    const int n0 = bx * 32, k0 = by * 32;
    const int tx = threadIdx.x & 31, ty = threadIdx.x >> 5;
    #pragma unroll
    for (int i = 0; i < 32; i += 8) {
        int k = k0 + ty + i, n = n0 + tx;
        s[ty + i][tx] = (k < K && n < N) ? W[(size_t)k * N + n] : 0.f;
    }
    __syncthreads();
    #pragma unroll
    for (int i = 0; i < 32; i += 8) {
        int n = n0 + ty + i, k = k0 + tx;
        if (n < N && k < K) WT[(size_t)n * K + k] = f2b(s[tx][ty + i]);
    }
}

__global__ __launch_bounds__(256) void prep_all_k(
        const float* __restrict__ Wih, const float* __restrict__ Whh,
        const float* __restrict__ frW, const float* __restrict__ b1W1,
        const float* __restrict__ b1W2, const float* __restrict__ b2W1,
        const float* __restrict__ b2W2, const float* __restrict__ encW,
        const float* __restrict__ aW1, const float* __restrict__ cW1,
        const float* __restrict__ aW3, const float* __restrict__ aW2,
        const float* __restrict__ cW2, const float* __restrict__ ab1,
        const float* __restrict__ cb1, const float* __restrict__ ab2,
        const float* __restrict__ cb2, const float* __restrict__ emb,
        const float* __restrict__ img, const float* __restrict__ box,
        unsigned short* __restrict__ WihT, unsigned short* __restrict__ WhhT,
        unsigned short* __restrict__ frWT, unsigned short* __restrict__ b1W1T,
        unsigned short* __restrict__ b1W2T, unsigned short* __restrict__ b2W1T,
        unsigned short* __restrict__ b2W2T, unsigned short* __restrict__ encWT,
        unsigned short* __restrict__ W1cT, unsigned short* __restrict__ W2cT,
        unsigned short* __restrict__ WT3, float* __restrict__ b1c,
        float* __restrict__ b2c, unsigned short* __restrict__ embB,
        unsigned short* __restrict__ A0)
{
    int bid = blockIdx.x;
    const int tid = threadIdx.x;
    if (bid < 768) { tileT_dev(Wih, WihT, 512, 1536, bid % 48, bid / 48); return; }
    bid -= 768;
    if (bid < 768) { tileT_dev(Whh, WhhT, 512, 1536, bid % 48, bid / 48); return; }
    bid -= 768;
    if (bid < 1152) { tileT_dev(frW, frWT, 2304, 512, bid % 16, bid / 16); return; }
    bid -= 1152;
    if (bid < 256) { tileT_dev(b1W1, b1W1T, 512, 512, bid % 16, bid / 16); return; }
    bid -= 256;
    if (bid < 256) { tileT_dev(b1W2, b1W2T, 512, 512, bid % 16, bid / 16); return; }
    bid -= 256;
    if (bid < 256) { tileT_dev(b2W1, b2W1T, 512, 512, bid % 16, bid / 16); return; }
    bid -= 256;
    if (bid < 256) { tileT_dev(b2W2, b2W2T, 512, 512, bid % 16, bid / 16); return; }
    bid -= 256;
    if (bid < 256) { tileT_dev(encW, encWT, 512, 512, bid % 16, bid / 16); return; }
    bid -= 256;
    if (bid < 32) { tileT_dev(aW1, W1cT, 512, 64, bid % 2, bid / 2); return; }
    bid -= 32;
    if (bid < 32) { tileT_dev(cW1, W1cT + (size_t)64 * 512, 512, 64, bid % 2, bid / 2); return; }
    bid -= 32;
    if (bid < 626) { tileT_dev(aW3, WT3, 64, 10000, bid % 313, bid / 313); return; }
    bid -= 626;
    if (bid < 64) {
        int idx = bid * 256 + tid;
        int j = idx >> 7, k = idx & 127;
        float v = 0.f;
        if (j < 64 && k < 64) v = aW2[(size_t)k * 64 + j];
        else if (j >= 64 && k >= 64) v = cW2[(size_t)(k - 64) * 64 + (j - 64)];
        W2cT[idx] = f2b(v);
        return;
    }
    bid -= 64;
    if (bid < 1) {
        if (tid < 128) b1c[tid] = (tid < 64) ? ab1[tid] : cb1[tid - 64];
        else { int i = tid - 128; b2c[i] = (i < 64) ? ab2[i] : cb2[i - 64]; }
        return;
    }
    bid -= 1;
    if (bid < 5056) {
        int idx = bid * 256 + tid;
        int row = idx >> 7, c4 = (idx & 127) * 4;
        float4 v = {0.f, 0.f, 0.f, 0.f};
        if (row < Vv) v = *(const float4*)(emb + (size_t)row * 512 + c4);
        ushort4 o; o.x = f2b(v.x); o.y = f2b(v.y); o.z = f2b(v.z); o.w = f2b(v.w);
        *(ushort4*)(embB + (size_t)row * 512 + c4) = o;
        return;
    }
    bid -= 5056;
    {
        int idx = bid * 256 + tid;
        int row = idx / 576, c4 = (idx - row * 576) * 4;
        float4 v = (c4 < 2048) ? *(const float4*)(img + (size_t)row * 2048 + c4)
                               : *(const float4*)(box + (size_t)row * 256 + (c4 - 2048));
        ushort4 o; o.x = f2b(v.x); o.y = f2b(v.y); o.z = f2b(v.z); o.w = f2b(v.w);
        *(ushort4*)(A0 + (size_t)row * 2304 + c4) = o;
    }
}

// ---------------- one GRU step (r6-proven): A preloaded, B via gload_lds ----------------
__global__ __launch_bounds__(256) void gru_step3_k(
        const unsigned short* __restrict__ Hprev,
        const unsigned short* __restrict__ WihT,
        const float* __restrict__ bih, const float* __restrict__ bhh,
        const unsigned short* __restrict__ GHemb,
        const float* __restrict__ emb, const int* __restrict__ acts, int t,
        unsigned short* __restrict__ Hout)
{
    __shared__ __align__(16) unsigned short sB[48 * 512];
    const int tid = threadIdx.x, w = tid >> 6, lane = tid & 63;
    const int l15 = lane & 15, lh = lane >> 4;
    const int d0 = blockIdx.x * 16;
    const int rows0 = blockIdx.y * 64 + w * 16;
    const unsigned short* Arow = Hprev + (size_t)(rows0 + l15) * 512 + lh * 8;
    b16x8 a[16];
    #pragma unroll
    for (int kk = 0; kk < 16; kk++) a[kk] = *(const b16x8*)(Arow + kk * 32);
    #pragma unroll
    for (int c = 0; c < 12; c++) {
        const int ch = w * 12 + c;
        const int g = ch >> 4, col = ch & 15;
        const int sl = lane ^ (ch & 7);
        gload16(WihT + (size_t)(g * 512 + d0 + col) * 512 + sl * 8, &sB[ch * 512]);
    }
    __syncthreads();
    f32x4 ar = (f32x4){0.f,0.f,0.f,0.f}, az = ar, an = ar;
    #pragma unroll
    for (int kk = 0; kk < 16; kk++) {
        const int sl = ((kk * 4 + lh) ^ (l15 & 7));
        b16x8 b0 = *(const b16x8*)(&sB[(l15) * 512 + sl * 8]);
        b16x8 b1 = *(const b16x8*)(&sB[(16 + l15) * 512 + sl * 8]);
        b16x8 b2 = *(const b16x8*)(&sB[(32 + l15) * 512 + sl * 8]);
        ar = __builtin_amdgcn_mfma_f32_16x16x32_bf16(a[kk], b0, ar, 0, 0, 0);
        az = __builtin_amdgcn_mfma_f32_16x16x32_bf16(a[kk], b1, az, 0, 0, 0);
        an = __builtin_amdgcn_mfma_f32_16x16x32_bf16(a[kk], b2, an, 0, 0, 0);
    }
    const int d = d0 + l15;
    const float bi0 = bih[d], bi1 = bih[512 + d], bi2 = bih[1024 + d];
    const float bh0 = bhh[d], bh1 = bhh[512 + d], bh2 = bhh[1024 + d];
    #pragma unroll
    for (int reg = 0; reg < 4; reg++) {
        const int row = rows0 + lh * 4 + reg;
        float hr = bh0, hz = bh1, hn = bh2, ix = 0.f;
        if (t) {
            const int ap = acts[row * Tlen + t - 1];
            const size_t gb = (size_t)ap * 1536;
            hr += b2f(GHemb[gb + d]);
            hz += b2f(GHemb[gb + 512 + d]);
            hn += b2f(GHemb[gb + 1024 + d]);
            ix = emb[(size_t)ap * 512 + d];
        }
        const float rr = fast_sig(ar[reg] + bi0 + hr);
        const float zz = fast_sig(az[reg] + bi1 + hz);
        const float nn = fast_tanh(an[reg] + bi2 + rr * hn);
        Hout[(size_t)row * 512 + d] = f2b((1.f - zz) * nn + zz * ix);
    }
}

// ---------------- logits: V-split MFMA + partial exp-sums ----------------
__global__ __launch_bounds__(256) void logits3_k(const unsigned short* __restrict__ A2b,
        const unsigned short* __restrict__ WT3, const float* __restrict__ b3,
        const float* __restrict__ wmask, float* __restrict__ Spart,
        float* __restrict__ Wmpart)
{
    __shared__ __align__(16) char Bs[64 * 144];
    __shared__ float bmS[64];
    const int tid = threadIdx.x, wid = tid >> 6, lane = tid & 63;
    const int r0 = blockIdx.x * 64;
    const int c0 = blockIdx.y * 640;
    const int cend = (c0 + 640 < 5056) ? c0 + 640 : 5056;
    const size_t abase = (size_t)(r0 + wid * 16 + (lane & 15)) * 128 + (lane >> 4) * 8;
    const b16x8 af0 = *(const b16x8*)(A2b + abase);
    const b16x8 af1 = *(const b16x8*)(A2b + abase + 32);
    float S[4] = {0.f, 0.f, 0.f, 0.f}, Wm[4] = {0.f, 0.f, 0.f, 0.f};
    for (int cc = c0; cc < cend; cc += 64) {
        __syncthreads();
        #pragma unroll
        for (int i = 0; i < 2; i++) {
            int e = tid + i * 256;
            int rr = e >> 3, slot = e & 7;
            b16x8 wv = *(const b16x8*)(WT3 + (size_t)(cc + rr) * 64 + slot * 8);
            *(b16x8*)(Bs + rr * 144 + slot * 16) = wv;
        }
        if (tid < 64) bmS[tid] = b3[cc + tid] + wmask[cc + tid];
        __syncthreads();
        #pragma unroll
        for (int ct = 0; ct < 4; ct++) {
            const int colb = (ct * 16 + (lane & 15)) * 144 + (lane >> 4) * 16;
            b16x8 bf0 = *(const b16x8*)(Bs + colb);
            b16x8 bf1 = *(const b16x8*)(Bs + colb + 64);
            f32x4 acc = (f32x4){0.f, 0.f, 0.f, 0.f};
            acc = __builtin_amdgcn_mfma_f32_16x16x32_bf16(af0, bf0, acc, 0, 0, 0);
            acc = __builtin_amdgcn_mfma_f32_16x16x32_bf16(af1, bf1, acc, 0, 0, 0);
            const float bm = bmS[ct * 16 + (lane & 15)];
            #pragma unroll
            for (int r = 0; r < 4; r++) {
                float l = acc[r] + bm;
                float e = __expf(l);
                S[r] += e;
                Wm[r] = fmaf(e, l, Wm[r]);
            }
        }
    }
    #pragma unroll
    for (int r = 0; r < 4; r++) {
        float s = S[r], w = Wm[r];
        #pragma unroll
        for (int o = 1; o < 16; o <<= 1) {
            s += __shfl_xor(s, o, 64);
            w += __shfl_xor(w, o, 64);
        }
        if ((lane & 15) == 0) {
            int row = r0 + wid * 16 + (lane >> 4) * 4 + r;
            Spart[blockIdx.y * BT + row] = s;
            Wmpart[blockIdx.y * BT + row] = w;
        }
    }
}

// ---------------- merged tail: entropy / logp / value / actions ----------------
__global__ __launch_bounds__(256) void tail_k(const float* __restrict__ Spart,
        const float* __restrict__ Wmpart, const unsigned short* __restrict__ L2b,
        const unsigned short* __restrict__ WT3, const float* __restrict__ b3,
        const float* __restrict__ wmask, const int* __restrict__ acts,
        const float* __restrict__ cw3, const float* __restrict__ cb3,
        float* __restrict__ out)
{
    const int bid = blockIdx.x, tid = threadIdx.x;
    if (bid < 80) {
        const int rt = bid * 256 + tid;
        float s = 0.f, wm = 0.f;
        #pragma unroll
        for (int j = 0; j < 8; j++) { s += Spart[j * BT + rt]; wm += Wmpart[j * BT + rt]; }
        const float l = logf(s);
        const int t = rt >> 10, b = rt & 1023;
        out[2 * BT + b * Tlen + t] = l - wm / s;
    } else if (bid < 160) {
        const int rt = (bid - 80) * 256 + tid;
        float s = 0.f;
        #pragma unroll
        for (int j = 0; j < 8; j++) s += Spart[j * BT + rt];
        const int t = rt >> 10, b = rt & 1023;
        const int a = acts[b * Tlen + t];
        const unsigned short* ar = L2b + (size_t)rt * 128;
        const unsigned short* wr = WT3 + (size_t)a * 64;
        float dot = 0.f;
        #pragma unroll 16
        for (int k = 0; k < 64; k++) dot = fmaf(b2f(ar[k]), b2f(wr[k]), dot);
        out[BT + b * Tlen + t] = dot + b3[a] + wmask[a] - logf(s);
    } else if (bid < 240) {
        const int rt = (bid - 160) * 256 + tid;
        const unsigned short* c = L2b + (size_t)rt * 128 + 64;
        float s = cb3[0];
        #pragma unroll 16
        for (int k = 0; k < 64; k++) s = fmaf(b2f(c[k]), cw3[k], s);
        const int t = rt >> 10, b = rt & 1023;
        out[3 * BT + b * Tlen + t] = s;
    } else {
        const int rt = (bid - 240) * 256 + tid;
        out[rt] = (float)acts[rt];
    }
}

extern "C" void kernel_launch(void* const* d_in, const int* in_sizes, int n_in,
                              void* d_out, int out_size, void* d_ws, size_t ws_size,
                              hipStream_t stream)
{
    const float* img  = (const float*)d_in[0];
    const float* box  = (const float*)d_in[1];
    const int*   acts = (const int*)d_in[2];
    const float* fr_W = (const float*)d_in[3];
    const float* fr_b = (const float*)d_in[4];
    const float* b1W1 = (const float*)d_in[5];
    const float* b1b1 = (const float*)d_in[6];
    const float* b1W2 = (const float*)d_in[7];
    const float* b1b2 = (const float*)d_in[8];
    const float* b2W1 = (const float*)d_in[9];
    const float* b2b1 = (const float*)d_in[10];
    const float* b2W2 = (const float*)d_in[11];
    const float* b2b2 = (const float*)d_in[12];
    const float* lng  = (const float*)d_in[13];
    const float* lnb  = (const float*)d_in[14];
    const float* encW = (const float*)d_in[15];
    const float* encb = (const float*)d_in[16];
    const float* emb  = (const float*)d_in[17];
    const float* Wih  = (const float*)d_in[18];
    const float* bih  = (const float*)d_in[19];
    const float* Whh  = (const float*)d_in[20];
    const float* bhh  = (const float*)d_in[21];
    const float* aW1  = (const float*)d_in[22];
    const float* ab1  = (const float*)d_in[23];
    const float* aW2  = (const float*)d_in[24];
    const float* ab2  = (const float*)d_in[25];
    const float* aW3  = (const float*)d_in[26];
    const float* ab3  = (const float*)d_in[27];
    const float* cW1  = (const float*)d_in[28];
    const float* cb1  = (const float*)d_in[29];
    const float* cW2  = (const float*)d_in[30];
    const float* cb2  = (const float*)d_in[31];
    const float* cW3  = (const float*)d_in[32];
    const float* cb3  = (const float*)d_in[33];
    const float* wmask= (const float*)d_in[34];
    float* out = (float*)d_out;

    // ---- workspace ----
    char* w = (char*)d_ws;
    unsigned short* WihT  = (unsigned short*)w; w += (size_t)786432 * 2;
    unsigned short* WhhT  = (unsigned short*)w; w += (size_t)786432 * 2;
    unsigned short* frWT  = (unsigned short*)w; w += (size_t)1179648 * 2;
    unsigned short* b1W1T = (unsigned short*)w; w += (size_t)262144 * 2;
    unsigned short* b1W2T = (unsigned short*)w; w += (size_t)262144 * 2;
    unsigned short* b2W1T = (unsigned short*)w; w += (size_t)262144 * 2;
    unsigned short* b2W2T = (unsigned short*)w; w += (size_t)262144 * 2;
    unsigned short* encWT = (unsigned short*)w; w += (size_t)262144 * 2;
    unsigned short* W1cT  = (unsigned short*)w; w += (size_t)65536 * 2;
    unsigned short* W2cT  = (unsigned short*)w; w += (size_t)16384 * 2;
    unsigned short* WT3   = (unsigned short*)w; w += (size_t)640000 * 2;
    float* b1c = (float*)w;                     w += 128 * 4;
    float* b2c = (float*)w;                     w += 128 * 4;
    unsigned short* embB  = (unsigned short*)w; w += (size_t)10112 * 512 * 2;
    unsigned short* GHemb = (unsigned short*)w; w += (size_t)10112 * 1536 * 2;
    unsigned short* HALLb = (unsigned short*)w; w += (size_t)10485760 * 2;
    unsigned short* L1b   = (unsigned short*)w; w += (size_t)2621440 * 2;
    unsigned short* L2b   = (unsigned short*)w; w += (size_t)2621440 * 2;
    unsigned short* HB0   = (unsigned short*)w; w += (size_t)524288 * 2;
    float* Spart = (float*)w;                   w += (size_t)8 * BT * 4;
    float* Wmpart= (float*)w;                   w += (size_t)8 * BT * 4;
    unsigned short* A0 = (unsigned short*)w;    w += (size_t)2359296 * 2;
    float* Xe  = (float*)w;                     w += (size_t)524288 * 4;
    float* T2  = (float*)w;                     w += (size_t)524288 * 4;
    float* Sf  = (float*)w;                     w += (size_t)524288 * 4;
    unsigned short* T1b = (unsigned short*)w;   w += (size_t)524288 * 2;
    unsigned short* T3b = (unsigned short*)w;   w += (size_t)524288 * 2;

    const dim3 blk(256);

    // 1. all weight prep
    prep_all_k<<<12083, blk, 0, stream>>>(Wih, Whh, fr_W, b1W1, b1W2, b2W1, b2W2,
            encW, aW1, cW1, aW3, aW2, cW2, ab1, cb1, ab2, cb2, emb, img, box,
            WihT, WhhT, frWT, b1W1T, b1W2T, b2W1T, b2W2T, encWT, W1cT, W2cT,
            WT3, b1c, b2c, embB, A0);

    // 2. union: GHemb big-GEMM ∥ encoder fr-GEMM
    big_fr_k<<<1076, blk, 0, stream>>>(embB, WhhT, GHemb, A0, frWT, fr_b, Xe);

    // 3-7. encoder (LN fused into consumers, residuals in producers)
    gemm_ln_bf_k<1, 0, 0, 1><<<dim3(8, 16), blk, 0, stream>>>(Xe, b1W1T, b1b1,
            nullptr, nullptr, nullptr, T1b);
    gemm_bf_k<0, 1, 0, 0, 1><<<dim3(8, 16), blk, 0, stream>>>(T1b, b1W2T, b1b2,
            Xe, T2, nullptr, 512, 512);
    gemm_ln_bf_k<1, 0, 0, 1><<<dim3(8, 16), blk, 0, stream>>>(T2, b2W1T, b2b1,
            nullptr, nullptr, nullptr, T3b);
    gemm_bf_k<0, 1, 0, 0, 1><<<dim3(8, 16), blk, 0, stream>>>(T3b, b2W2T, b2b2,
            Xe, Sf, nullptr, 512, 512);
    gemm_ln_bf_k<0, 1, 0, 1><<<dim3(8, 16), blk, 0, stream>>>(Sf, encWT, encb,
            lng, lnb, nullptr, HB0);

    // 8-27. GRU scan
    for (int t = 0; t < Tlen; ++t) {
        const unsigned short* Hprev = t ? HALLb + (size_t)(t - 1) * 524288 : HB0;
        gru_step3_k<<<dim3(32, 16), blk, 0, stream>>>(Hprev, WihT, bih, bhh,
                GHemb, emb, acts, t, HALLb + (size_t)t * 524288);
    }

    // 28-31. heads (two LDS-staged GEMMs, proven) + logits + tail
    gemm_bf_k<2, 0, 1, 0, 0><<<dim3(2, 320), blk, 0, stream>>>(HALLb, W1cT, b1c,
            nullptr, nullptr, L1b, 128, 512);
    gemm_bf_k<2, 0, 1, 0, 0><<<dim3(2, 320), blk, 0, stream>>>(L1b, W2cT, b2c,
            nullptr, nullptr, L2b, 128, 128);
    logits3_k<<<dim3(320, 8), blk, 0, stream>>>(L2b, WT3, ab3, wmask, Spart, Wmpart);
    tail_k<<<320, blk, 0, stream>>>(Spart, Wmpart, L2b, WT3, ab3, wmask, acts,
            cW3, cb3, out);
}